// Round 5
// baseline (621.136 us; speedup 1.0000x reference)
//
#include <hip/hip_runtime.h>
#include <cstdint>
#include <cstddef>

#define T_DIM 2048
#define D_DIM 2048
#define HI_N 4
#define DI_N 64
#define H_N 16
#define DH_N 128
#define TOPK_N 512
#define NEG_F (-1e9f)
#define FA_NEG (-1e30f)

typedef __attribute__((ext_vector_type(8))) short short8;
typedef __attribute__((ext_vector_type(4))) float f32x4;
typedef unsigned short ushort_t;

__device__ __forceinline__ unsigned short f2bf(float f) {
  unsigned u = __float_as_uint(f);
  u += 0x7FFFu + ((u >> 16) & 1u);   // RNE
  return (unsigned short)(u >> 16);
}
__device__ __forceinline__ float bf2f(unsigned short b) {
  return __uint_as_float((unsigned)b << 16);
}

#define GLDS(g, l) __builtin_amdgcn_global_load_lds( \
    (const __attribute__((address_space(1))) unsigned int*)(g), \
    (__attribute__((address_space(3))) unsigned int*)(l), 16, 0, 0)

// ---------------------------------------------------------------------------
// Fused indexer projections (fp32): qi[2048][256], ki[2048][64], wI[2048][4].
// Single-wave blocks (64 thr), 32x32 tiles, grid (11, 64) = 704 blocks.
// A row-major [row][k] read as float4 ALONG k (broadcast across tx);
// B [k][col] read as float4 per k (broadcast across ty). 34-float pad ->
// every LDS access <=2-way. 4x4 acc/thread; 64 FMA per 8 LDS reads.
// Per-output k accumulation order identical to prior versions (bitwise-same).
// ---------------------------------------------------------------------------
__global__ __launch_bounds__(64) void idx_proj(const float* __restrict__ x,
                                               const float* __restrict__ Wq_idx,
                                               const float* __restrict__ Wk_idx,
                                               const float* __restrict__ Ww_idx,
                                               float* __restrict__ qi,
                                               float* __restrict__ ki,
                                               float* __restrict__ wI) {
  __shared__ float As[2][32][34];   // [buf][row][k]
  __shared__ float Bs[2][32][34];   // [buf][k][col]
  const int bm = blockIdx.y << 5;
  const int sl = blockIdx.x;
  const float* B; float* C; int ldB, cb, ncols;
  if (sl < 8)       { B = Wq_idx; C = qi; ldB = 256; cb = sl << 5;       ncols = 32; }
  else if (sl < 10) { B = Wk_idx; C = ki; ldB = 64;  cb = (sl - 8) << 5; ncols = 32; }
  else              { B = Ww_idx; C = wI; ldB = 4;   cb = 0;             ncols = 4;  }
  const int tid = threadIdx.x;      // 0..63 (one wave)
  const int tx = tid & 7;           // col group: cols tx*4..+3
  const int ty = tid >> 3;          // row group: rows ty*4..+3
  const int sr = tid >> 2;          // staging row base 0..15 (+16)
  const int sc = (tid & 3) << 3;    // staging col base 0,8,16,24 (+4)

  float acc[4][4] = {};
  float4 ga[2][2], gb[2][2];        // [p(row+16p)][q(col+4q)]

  // ---- prologue: load k0=0, stage into buf 0 ----
#pragma unroll
  for (int p = 0; p < 2; ++p)
#pragma unroll
    for (int q = 0; q < 2; ++q) {
      ga[p][q] = *(const float4*)&x[(size_t)(bm + sr + 16 * p) * 2048 + sc + 4 * q];
      gb[p][q] = make_float4(0.f, 0.f, 0.f, 0.f);
      if (sc + 4 * q < ncols)
        gb[p][q] = *(const float4*)&B[(size_t)(sr + 16 * p) * ldB + cb + sc + 4 * q];
    }
#pragma unroll
  for (int p = 0; p < 2; ++p)
#pragma unroll
    for (int q = 0; q < 2; ++q) {
      *(float4*)&As[0][sr + 16 * p][sc + 4 * q] = ga[p][q];
      *(float4*)&Bs[0][sr + 16 * p][sc + 4 * q] = gb[p][q];
    }

  int pbuf = 0;
  for (int k0 = 0; k0 < 2048; k0 += 32) {
    __syncthreads();   // single wave: cheap; makes buf pbuf stores visible
    const bool more = (k0 + 32) < 2048;
    if (more) {
#pragma unroll
      for (int p = 0; p < 2; ++p)
#pragma unroll
        for (int q = 0; q < 2; ++q) {
          ga[p][q] = *(const float4*)&x[(size_t)(bm + sr + 16 * p) * 2048 + k0 + 32 + sc + 4 * q];
          if (sc + 4 * q < ncols)
            gb[p][q] = *(const float4*)&B[(size_t)(k0 + 32 + sr + 16 * p) * ldB + cb + sc + 4 * q];
        }
    }
    // ---- compute over buf pbuf: 8 chunks of 4 k ----
#pragma unroll
    for (int kk = 0; kk < 32; kk += 4) {
      float4 av4[4], bv4[4];
#pragma unroll
      for (int i = 0; i < 4; ++i)
        av4[i] = *(const float4*)&As[pbuf][(ty << 2) + i][kk];
#pragma unroll
      for (int t = 0; t < 4; ++t)
        bv4[t] = *(const float4*)&Bs[pbuf][kk + t][tx << 2];
      float av[4][4] = {{av4[0].x, av4[0].y, av4[0].z, av4[0].w},
                        {av4[1].x, av4[1].y, av4[1].z, av4[1].w},
                        {av4[2].x, av4[2].y, av4[2].z, av4[2].w},
                        {av4[3].x, av4[3].y, av4[3].z, av4[3].w}};
      float bv[4][4] = {{bv4[0].x, bv4[0].y, bv4[0].z, bv4[0].w},
                        {bv4[1].x, bv4[1].y, bv4[1].z, bv4[1].w},
                        {bv4[2].x, bv4[2].y, bv4[2].z, bv4[2].w},
                        {bv4[3].x, bv4[3].y, bv4[3].z, bv4[3].w}};
#pragma unroll
      for (int i = 0; i < 4; ++i)
#pragma unroll
        for (int t = 0; t < 4; ++t)   // k ascends for each (i,j): bitwise-safe
#pragma unroll
          for (int j = 0; j < 4; ++j)
            acc[i][j] += av[i][t] * bv[t][j];
    }
    if (more) {
#pragma unroll
      for (int p = 0; p < 2; ++p)
#pragma unroll
        for (int q = 0; q < 2; ++q) {
          *(float4*)&As[1 - pbuf][sr + 16 * p][sc + 4 * q] = ga[p][q];
          *(float4*)&Bs[1 - pbuf][sr + 16 * p][sc + 4 * q] = gb[p][q];
        }
    }
    pbuf ^= 1;
  }

  // ---- store 4x4 ----
#pragma unroll
  for (int i = 0; i < 4; ++i) {
    const int m = bm + (ty << 2) + i;
    const int n0 = tx << 2;
    if (n0 + 3 < ncols) {
      *(float4*)&C[(size_t)m * ldB + cb + n0] =
          make_float4(acc[i][0], acc[i][1], acc[i][2], acc[i][3]);
    } else {
#pragma unroll
      for (int j = 0; j < 4; ++j)
        if (n0 + j < ncols) C[(size_t)m * ldB + cb + n0 + j] = acc[i][j];
    }
  }
}

// ---------------------------------------------------------------------------
// casts / transposes
// ---------------------------------------------------------------------------
__global__ __launch_bounds__(256) void cast_bf16(const float* __restrict__ in,
                                                 ushort_t* __restrict__ out) {
  int i = (blockIdx.x * 256 + threadIdx.x) * 4;
  float4 f = *(const float4*)(in + i);
  ushort4 o;
  o.x = f2bf(f.x); o.y = f2bf(f.y); o.z = f2bf(f.z); o.w = f2bf(f.w);
  *(ushort4*)(out + i) = o;
}

// in[R][C] f32 -> out[C][R] bf16
__global__ __launch_bounds__(256) void cast_transpose(const float* __restrict__ in,
                                                      ushort_t* __restrict__ out,
                                                      int R, int C) {
  __shared__ float tile[32][33];
  const int bx = blockIdx.x * 32;
  const int by = blockIdx.y * 32;
  const int tx = threadIdx.x & 31, ty = threadIdx.x >> 5;
#pragma unroll
  for (int i = 0; i < 32; i += 8)
    tile[ty + i][tx] = in[(size_t)(by + ty + i) * C + bx + tx];
  __syncthreads();
#pragma unroll
  for (int i = 0; i < 32; i += 8)
    out[(size_t)(bx + ty + i) * R + by + tx] = f2bf(tile[tx][ty + i]);
}

// bf16 [T][ldin] -> [C][T] (transpose 64x64 tiles), ldin-strided input
__global__ __launch_bounds__(256) void transpose_bf(const ushort_t* __restrict__ in,
                                                    ushort_t* __restrict__ out,
                                                    int ldin) {
  __shared__ ushort_t tile[64][68];
  const int bx = blockIdx.x * 64;  // col base (input)
  const int by = blockIdx.y * 64;  // row base (input)
  const int tid = threadIdx.x;
#pragma unroll
  for (int p = 0; p < 4; ++p) {
    int r = p * 16 + (tid >> 4), c0 = (tid & 15) * 4;
    *(ushort4*)&tile[r][c0] = *(const ushort4*)(in + (size_t)(by + r) * ldin + bx + c0);
  }
  __syncthreads();
#pragma unroll
  for (int p = 0; p < 4; ++p) {
    int r = p * 16 + (tid >> 4), c0 = (tid & 15) * 4;
    ushort4 o;
    o.x = tile[c0 + 0][r]; o.y = tile[c0 + 1][r];
    o.z = tile[c0 + 2][r]; o.w = tile[c0 + 3][r];
    *(ushort4*)(out + (size_t)(bx + r) * T_DIM + by + c0) = o;
  }
}

// ---------------------------------------------------------------------------
// bf16 MFMA GEMM: C[M,N] = A[M,K] @ Bt[N,K]^T (m97 128^2 structure; used for Wo)
// ---------------------------------------------------------------------------
template <int OUT_BF16>
__global__ __launch_bounds__(256) void gemm_bt(const ushort_t* __restrict__ A,
                                               const ushort_t* __restrict__ Bt,
                                               void* __restrict__ C,
                                               int M, int N, int K) {
  __shared__ __attribute__((aligned(16))) ushort_t As[128 * 64];
  __shared__ __attribute__((aligned(16))) ushort_t Bs[128 * 64];
  const int bm = blockIdx.y << 7;
  const int bn = blockIdx.x << 7;
  const int tid = threadIdx.x;
  const int lane = tid & 63;
  const int wv = tid >> 6;
  const int wm = (wv >> 1) << 6;
  const int wn = (wv & 1) << 6;

  f32x4 acc[4][4] = {};

  const int sr = tid >> 3;
  const int sc = (tid & 7) << 3;
  const ushort_t* ga = A + (size_t)(bm + sr) * K + sc;
  const ushort_t* gb = Bt + (size_t)(bn + sr) * K + sc;
  const size_t rstep = (size_t)32 * K;

  for (int k0 = 0; k0 < K; k0 += 64) {
#pragma unroll
    for (int i = 0; i < 4; ++i) {
      GLDS(ga + i * rstep + k0, As + i * 2048 + tid * 8);
      GLDS(gb + i * rstep + k0, Bs + i * 2048 + tid * 8);
    }
    __syncthreads();
#pragma unroll
    for (int ks = 0; ks < 2; ++ks) {
      short8 af[4], bfr[4];
      const int kk = (ks << 5) + ((lane >> 4) << 3);
#pragma unroll
      for (int i = 0; i < 4; ++i) {
        af[i]  = *(const short8*)(As + (wm + (i << 4) + (lane & 15)) * 64 + kk);
        bfr[i] = *(const short8*)(Bs + (wn + (i << 4) + (lane & 15)) * 64 + kk);
      }
#pragma unroll
      for (int i = 0; i < 4; ++i)
#pragma unroll
        for (int j = 0; j < 4; ++j)
          acc[i][j] = __builtin_amdgcn_mfma_f32_16x16x32_bf16(af[i], bfr[j], acc[i][j], 0, 0, 0);
    }
    __syncthreads();
  }

  const int lrow = (lane >> 4) << 2;
  const int lcol = lane & 15;
#pragma unroll
  for (int i = 0; i < 4; ++i) {
    const int row = bm + wm + (i << 4) + lrow;
#pragma unroll
    for (int j = 0; j < 4; ++j) {
      const int col = bn + wn + (j << 4) + lcol;
#pragma unroll
      for (int r = 0; r < 4; ++r) {
        if (OUT_BF16)
          ((ushort_t*)C)[(size_t)(row + r) * N + col] = f2bf(acc[i][j][r]);
        else
          ((float*)C)[(size_t)(row + r) * N + col] = acc[i][j][r];
      }
    }
  }
}

// ---------------------------------------------------------------------------
// 256x256-tile 8-phase bf16 GEMM (T2+T3+T4+T5), C bf16 = A[M,K] @ Bt[N,K]^T.
// ---------------------------------------------------------------------------
__global__ __launch_bounds__(512, 2) void gemm256_bt(const ushort_t* __restrict__ A,
                                                     const ushort_t* __restrict__ Bt,
                                                     ushort_t* __restrict__ C,
                                                     int M, int N, int K) {
  __shared__ __attribute__((aligned(16))) ushort_t Ab[2][256 * 64];
  __shared__ __attribute__((aligned(16))) ushort_t Bb[2][256 * 64];
  const int bm = blockIdx.y << 8;
  const int bn = blockIdx.x << 8;
  const int tid = threadIdx.x;
  const int lane = tid & 63;
  const int wid = tid >> 6;
  const int wr = wid >> 2;          // 0..1  (M half)
  const int wc = wid & 3;           // 0..3  (N quarter)
  const int l15 = lane & 15, l4 = lane >> 4;
  const int srow = tid >> 3;        // 0..63
  const int schunk = tid & 7;
  const int swc = (schunk ^ (srow & 7)) << 3;   // pre-swizzled source col
  const int NT = K >> 6;

  f32x4 acc[8][4] = {};

#define STAGE_A(b, h, kt) { \
    const ushort_t* g_ = A + (size_t)(bm + (h) * 64 + srow) * K + (kt) * 64 + swc; \
    GLDS(g_, Ab[b] + ((h) * 64 + srow) * 64 + (schunk << 3)); \
    GLDS(g_ + (size_t)128 * K, Ab[b] + (128 + (h) * 64 + srow) * 64 + (schunk << 3)); }

#define STAGE_B(b, h, kt) { \
    const int br_ = ((srow >= 32) ? 64 : 0) + (h) * 32 + (srow & 31); \
    const ushort_t* g_ = Bt + (size_t)(bn + br_) * K + (kt) * 64 + swc; \
    GLDS(g_, Bb[b] + br_ * 64 + (schunk << 3)); \
    GLDS(g_ + (size_t)128 * K, Bb[b] + (128 + br_) * 64 + (schunk << 3)); }

#define VMW(n) asm volatile("s_waitcnt vmcnt(" #n ")" ::: "memory")

#define PHASE(b, qm, qn, STG, WT) { \
    short8 paf[4][2], pbf[2][2]; \
    _Pragma("unroll") for (int m_ = 0; m_ < 4; ++m_) { \
      const int Ra_ = wr * 128 + (qm) * 64 + m_ * 16 + l15; \
      _Pragma("unroll") for (int ks_ = 0; ks_ < 2; ++ks_) \
        paf[m_][ks_] = *(const short8*)(Ab[b] + Ra_ * 64 + ((((ks_ << 2) + l4) ^ (Ra_ & 7)) << 3)); } \
    _Pragma("unroll") for (int n_ = 0; n_ < 2; ++n_) { \
      const int Rb_ = wc * 64 + (qn) * 32 + n_ * 16 + l15; \
      _Pragma("unroll") for (int ks_ = 0; ks_ < 2; ++ks_) \
        pbf[n_][ks_] = *(const short8*)(Bb[b] + Rb_ * 64 + ((((ks_ << 2) + l4) ^ (Rb_ & 7)) << 3)); } \
    STG; \
    WT; \
    asm volatile("" ::: "memory"); \
    __builtin_amdgcn_s_barrier(); \
    asm volatile("s_waitcnt lgkmcnt(0)" ::: "memory"); \
    __builtin_amdgcn_sched_barrier(0); \
    __builtin_amdgcn_s_setprio(1); \
    _Pragma("unroll") for (int m_ = 0; m_ < 4; ++m_) \
      _Pragma("unroll") for (int n_ = 0; n_ < 2; ++n_) \
        _Pragma("unroll") for (int ks_ = 0; ks_ < 2; ++ks_) \
          acc[(qm) * 4 + m_][(qn) * 2 + n_] = __builtin_amdgcn_mfma_f32_16x16x32_bf16( \
              paf[m_][ks_], pbf[n_][ks_], acc[(qm) * 4 + m_][(qn) * 2 + n_], 0, 0, 0); \
    __builtin_amdgcn_s_setprio(0); \
    asm volatile("" ::: "memory"); \
    __builtin_amdgcn_s_barrier(); \
    asm volatile("" ::: "memory"); }

  // prologue = virtual P3..P8: tile0 all 4 halves -> b0; tile1 ev halves -> b1
  STAGE_A(0, 0, 0); STAGE_B(0, 0, 0); STAGE_A(0, 1, 0); STAGE_B(0, 1, 0);
  STAGE_A(1, 0, 1); STAGE_B(1, 0, 1);
  VMW(8);                      // confirms b0 A-ev, B-ev
  asm volatile("" ::: "memory");
  __builtin_amdgcn_s_barrier();
  asm volatile("" ::: "memory");

  for (int j = 0; j < NT / 2 - 1; ++j) {
    const int t = j * 2;
    PHASE(0, 0, 0, STAGE_A(1, 1, t + 1), VMW(6));   // confirms thru b0 B-od
    PHASE(0, 0, 1, STAGE_B(1, 1, t + 1), );
    PHASE(0, 1, 0, STAGE_A(0, 0, t + 2), );
    PHASE(0, 1, 1, STAGE_B(0, 0, t + 2), VMW(8));   // confirms thru b1 ev
    PHASE(1, 0, 0, STAGE_A(0, 1, t + 2), VMW(6));   // confirms thru b1 B-od
    PHASE(1, 0, 1, STAGE_B(0, 1, t + 2), );
    PHASE(1, 1, 0, STAGE_A(1, 0, t + 3), );
    PHASE(1, 1, 1, STAGE_B(1, 0, t + 3), VMW(8));   // confirms thru b0 ev
  }
  // tail: tiles NT-2 (b0, fully staged), NT-1 (b1: ev staged, od staged here)
  PHASE(0, 0, 0, STAGE_A(1, 1, NT - 1), VMW(6));
  PHASE(0, 0, 1, STAGE_B(1, 1, NT - 1), );
  PHASE(0, 1, 0, , );
  PHASE(0, 1, 1, , VMW(4));    // confirms b1 ev
  PHASE(1, 0, 0, , VMW(0));    // confirms b1 od
  PHASE(1, 0, 1, , );
  PHASE(1, 1, 0, , );
  PHASE(1, 1, 1, , );

#undef STAGE_A
#undef STAGE_B
#undef VMW
#undef PHASE

  // epilogue
#pragma unroll
  for (int i = 0; i < 8; ++i) {
    const int row = bm + wr * 128 + i * 16 + l4 * 4;
#pragma unroll
    for (int j2 = 0; j2 < 4; ++j2) {
      const int col = bn + wc * 64 + j2 * 16 + l15;
#pragma unroll
      for (int r = 0; r < 4; ++r)
        C[(size_t)(row + r) * N + col] = f2bf(acc[i][j2][r]);
    }
  }
}

// ---------------------------------------------------------------------------
// Lightning indexer scores, register-tiled 64x64 fp32
// ---------------------------------------------------------------------------
__global__ __launch_bounds__(256) void idx_scores_rt(const float* __restrict__ qi,
                                                     const float* __restrict__ ki,
                                                     const float* __restrict__ w,
                                                     float* __restrict__ out) {
  const int t0 = blockIdx.y << 6, s0 = blockIdx.x << 6;
  const int tid = threadIdx.x;
  const int tx = tid & 15, ty = tid >> 4;
  if (s0 > t0 + 63) {  // fully above diagonal: NEG fill (ws is poisoned!)
    const float4 nf = make_float4(NEG_F, NEG_F, NEG_F, NEG_F);
#pragma unroll
    for (int i = 0; i < 4; ++i) {
      int m = t0 + (ty << 2) + i;
      *(float4*)&out[(size_t)m * T_DIM + s0 + (tx << 2)] = nf;
    }
    return;
  }
  __shared__ float As[16][64];   // [kk][t]
  __shared__ float Bs[16][64];   // [kk][s]
  __shared__ float wsh[64][4];
  if (tid < 64) *(float4*)wsh[tid] = *(const float4*)&w[(size_t)(t0 + tid) * 4];
  const int am = tid >> 2;          // 0..63
  const int ak = (tid & 3) << 2;    // 0,4,8,12
  float oacc[4][4] = {};
#pragma unroll
  for (int h = 0; h < HI_N; ++h) {
    float dacc[4][4] = {};
    for (int k0 = 0; k0 < DI_N; k0 += 16) {
      float4 qa = *(const float4*)&qi[(size_t)(t0 + am) * 256 + h * DI_N + k0 + ak];
      float4 kb = *(const float4*)&ki[(size_t)(s0 + am) * DI_N + k0 + ak];
      __syncthreads();
      As[ak + 0][am] = qa.x; As[ak + 1][am] = qa.y;
      As[ak + 2][am] = qa.z; As[ak + 3][am] = qa.w;
      Bs[ak + 0][am] = kb.x; Bs[ak + 1][am] = kb.y;
      Bs[ak + 2][am] = kb.z; Bs[ak + 3][am] = kb.w;
      __syncthreads();
#pragma unroll
      for (int kk = 0; kk < 16; ++kk) {
        float4 a4 = *(const float4*)&As[kk][ty << 2];
        float4 b4 = *(const float4*)&Bs[kk][tx << 2];
        float av[4] = {a4.x, a4.y, a4.z, a4.w};
        float bv[4] = {b4.x, b4.y, b4.z, b4.w};
#pragma unroll
        for (int i = 0; i < 4; ++i)
#pragma unroll
          for (int j = 0; j < 4; ++j) dacc[i][j] += av[i] * bv[j];
      }
    }
#pragma unroll
    for (int i = 0; i < 4; ++i) {
      float wh = wsh[(ty << 2) + i][h];
#pragma unroll
      for (int j = 0; j < 4; ++j) oacc[i][j] += fmaxf(dacc[i][j], 0.f) * wh;
    }
  }
#pragma unroll
  for (int i = 0; i < 4; ++i) {
    int m = t0 + (ty << 2) + i;
    int n0 = s0 + (tx << 2);
    float4 r;
    r.x = (n0 + 0 > m) ? NEG_F : oacc[i][0];
    r.y = (n0 + 1 > m) ? NEG_F : oacc[i][1];
    r.z = (n0 + 2 > m) ? NEG_F : oacc[i][2];
    r.w = (n0 + 3 > m) ? NEG_F : oacc[i][3];
    *(float4*)&out[(size_t)m * T_DIM + n0] = r;
  }
}

// ---------------------------------------------------------------------------
// Per-row top-512 -> bitmask. Radix-histogram select, jax tie semantics.
// ---------------------------------------------------------------------------
__global__ __launch_bounds__(256) void select_mask(const float* __restrict__ scores,
                                                   unsigned long long* __restrict__ maskbits) {
  const int t = blockIdx.x, tid = threadIdx.x;
  __shared__ unsigned int hist[256];
  __shared__ unsigned int s_prefix, s_krem;
  __shared__ unsigned char bytes[256];
  unsigned int uv[8];
  const float* row = scores + (size_t)t * T_DIM;
  {
    float4 f0 = *(const float4*)(row + tid * 8);
    float4 f1 = *(const float4*)(row + tid * 8 + 4);
    float fv[8] = {f0.x, f0.y, f0.z, f0.w, f1.x, f1.y, f1.z, f1.w};
#pragma unroll
    for (int j = 0; j < 8; ++j) {
      unsigned u = __float_as_uint(fv[j]);
      uv[j] = (u & 0x80000000u) ? ~u : (u | 0x80000000u);
    }
  }
  if (tid == 0) { s_prefix = 0u; s_krem = TOPK_N; }
  for (int p = 0; p < 4; ++p) {
    const int sh = 24 - 8 * p;
    hist[tid] = 0;
    __syncthreads();
    const unsigned pm = p ? (0xFFFFFFFFu << (32 - 8 * p)) : 0u;
    const unsigned prefix = s_prefix;
#pragma unroll
    for (int j = 0; j < 8; ++j)
      if ((uv[j] & pm) == prefix) atomicAdd(&hist[(uv[j] >> sh) & 255], 1u);
    __syncthreads();
    if (tid == 0) {
      unsigned krem = s_krem, cum = 0;
      int b = 255;
      for (;; --b) { cum += hist[b]; if (cum >= krem) break; }
      s_prefix = prefix | ((unsigned)b << sh);
      s_krem = krem - (cum - hist[b]);
    }
    __syncthreads();
  }
  const unsigned V = s_prefix;
  const int kr = (int)s_krem;
  int eqc = 0;
#pragma unroll
  for (int j = 0; j < 8; ++j) eqc += (uv[j] == V);
  __syncthreads();
  hist[tid] = (unsigned)eqc;
  __syncthreads();
  for (int off = 1; off < 256; off <<= 1) {
    int v = (int)hist[tid];
    if (tid >= off) v += (int)hist[tid - off];
    __syncthreads();
    hist[tid] = (unsigned)v;
    __syncthreads();
  }
  int run = (int)hist[tid] - eqc;
  unsigned char byte = 0;
#pragma unroll
  for (int j = 0; j < 8; ++j) {
    bool eq = (uv[j] == V);
    bool take = (uv[j] > V) || (eq && run < kr);
    run += eq;
    byte |= (unsigned char)(take ? (1u << j) : 0u);
  }
  bytes[tid] = byte;
  __syncthreads();
  if (tid < 32) {
    unsigned long long wqw = 0;
#pragma unroll
    for (int b = 0; b < 8; ++b)
      wqw |= (unsigned long long)bytes[tid * 8 + b] << (8 * b);
    maskbits[(size_t)t * 32 + tid] = wqw;
  }
}

// ---------------------------------------------------------------------------
// Flash masked attention (bf16 MFMA), SWAPPED-operand QK^T.
// ---------------------------------------------------------------------------
__global__ __launch_bounds__(256, 1) void flash_attn(
    const ushort_t* __restrict__ q, const ushort_t* __restrict__ k,
    const ushort_t* __restrict__ vt, const unsigned long long* __restrict__ maskbits,
    ushort_t* __restrict__ attn, int ldqk) {
  __shared__ __attribute__((aligned(16))) ushort_t Ks[2][128 * 128];
  __shared__ __attribute__((aligned(16))) ushort_t Vts[128 * 128];
  __shared__ __attribute__((aligned(16))) ushort_t Ps[128 * 136];

  const int tt = blockIdx.x;
  const int h  = blockIdx.y;
  const int t0 = tt << 7;
  const int tid = threadIdx.x;
  const int lane = tid & 63;
  const int wv = tid >> 6;              // wave id; owns q rows [wv*32, +32)
  const int l15 = lane & 15, l4 = lane >> 4;
  const int e3 = l15 & 7;                                  // read-side swizzle
  const int scol = (((tid & 15) ^ ((tid >> 4) & 7)) << 3); // staging source col

  // ---- stage Q (inverse-swizzled source) into Ks[0], read q fragments ----
  {
    const ushort_t* gq = q + (size_t)(t0 + (tid >> 4)) * ldqk + h * DH_N + scol;
#pragma unroll
    for (int p = 0; p < 8; ++p)
      GLDS(gq + (size_t)p * 16 * ldqk, Ks[0] + p * 2048 + tid * 8);
  }
  asm volatile("s_waitcnt vmcnt(0)" ::: "memory");
  __builtin_amdgcn_s_barrier();
  asm volatile("" ::: "memory");
  short8 qfrag[4][2];   // [ks][j]: Q rows wv*32 + j*16 + l15
#pragma unroll
  for (int ks = 0; ks < 4; ++ks)
#pragma unroll
    for (int j = 0; j < 2; ++j)
      qfrag[ks][j] = *(const short8*)(Ks[0] + (wv * 32 + j * 16 + l15) * 128 +
                                      ((((ks << 2) + l4) ^ e3) << 3));
  asm volatile("s_waitcnt lgkmcnt(0)" ::: "memory");
  __builtin_amdgcn_s_barrier();
  asm volatile("" ::: "memory");

  f32x4 acc[8][2] = {};              // O^T: [d-tile][q-tile]
  float m_reg[2] = {-INFINITY, -INFINITY};
  float l_reg[2] = {0.f, 0.f};
  const int nst = (tt < 4) ? 4 : (tt + 1);
  const float rsc = 0.08838834764831845f;  // 1/sqrt(128)

  // issue K(0) into Ks[0] (overwrites Q staging; qfrag already in registers)
  {
    const ushort_t* gk = k + (size_t)(tid >> 4) * ldqk + h * DH_N + scol;
#pragma unroll
    for (int p = 0; p < 8; ++p)
      GLDS(gk + (size_t)p * 16 * ldqk, Ks[0] + p * 2048 + tid * 8);
  }

  for (int st = 0; st < nst; ++st) {
    const int s0 = st << 7;
    const bool pf = (st + 1) < nst;

    // [A] all waves done with PV of st-1 -> Vts free for overwrite
    asm volatile("" ::: "memory");
    __builtin_amdgcn_s_barrier();
    asm volatile("" ::: "memory");

    // [B] mask words (4/lane)
    unsigned long long mw[2][2];
    {
      const int wbase = s0 >> 6;
#pragma unroll
      for (int j = 0; j < 2; ++j)
#pragma unroll
        for (int wd = 0; wd < 2; ++wd)
          mw[j][wd] = maskbits[(size_t)(t0 + wv * 32 + j * 16 + l15) * 32 + wbase + wd];
    }
    // [C] V(st) -> Vts (8 loads); consumed in PV (latency hidden)
    {
      const ushort_t* gv = vt + (size_t)(h * DH_N + (tid >> 4)) * T_DIM + s0 + scol;
#pragma unroll
      for (int p = 0; p < 8; ++p)
        GLDS(gv + (size_t)p * 16 * T_DIM, Vts + p * 2048 + tid * 8);
    }
    asm volatile("" ::: "memory");  // order: V strictly before K-prefetch
    // [D] K(st+1) prefetch into other buffer (8 loads)
    if (pf) {
      const ushort_t* gk = k + (size_t)(s0 + 128 + (tid >> 4)) * ldqk + h * DH_N + scol;
      ushort_t* dst = Ks[(st + 1) & 1];
#pragma unroll
      for (int p = 0; p < 8; ++p)
        GLDS(gk + (size_t)p * 16 * ldqk, dst + p * 2048 + tid * 8);
    }
    // [E] drain K(st) only: 4(mask)+8(V)+8(K+1) newer ops stay in flight
    if (pf) asm volatile("s_waitcnt vmcnt(20)" ::: "memory");
    else    asm volatile("s_waitcnt vmcnt(12)" ::: "memory");
    __builtin_amdgcn_s_barrier();   // [F] K(st) visible to all waves
    asm volatile("" ::: "memory");

    // ---- QK^T (swapped): sacc[i][j] rows = s, cols = q ----
    const ushort_t* Kb = Ks[st & 1];
    f32x4 sacc[8][2] = {};
    __builtin_amdgcn_s_setprio(1);
#pragma unroll
    for (int ks = 0; ks < 4; ++ks) {
      const int co = ((((ks << 2) + l4) ^ e3) << 3);
      short8 af[8];
#pragma unroll
      for (int i = 0; i < 8; ++i)
        af[i] = *(const short8*)(Kb + (i * 16 + l15) * 128 + co);
#pragma unroll
      for (int i = 0; i < 8; ++i)
#pragma unroll
        for (int j = 0; j < 2; ++j)
          sacc[i][j] = __builtin_amdgcn_mfma_f32_16x16x32_bf16(af[i], qfrag[ks][j], sacc[i][j], 0, 0, 0);
    }
    __builtin_amdgcn_s_setprio(0);

    // ---- mask + scale: s = i*16 + l4*4 + r ----
#pragma unroll
    for (int i = 0; i < 8; ++i)
#pragma unroll
      for (int j = 0; j < 2; ++j)
#pragma unroll
        for (int r = 0; r < 4; ++r) {
          bool sel = (mw[j][i >> 2] >> ((i & 3) * 16 + l4 * 4 + r)) & 1;
          sacc[i][j][r] = sel ? sacc[i][j][r] * rsc : FA_NEG;
        }

    // ---- in-register online softmax (per q column j) ----
    float alpha[2];
#pragma unroll
    for (int j = 0; j < 2; ++j) {
      float pm = sacc[0][j][0];
#pragma unroll
      for (int i = 0; i < 8; ++i)
#pragma unroll
        for (int r = 0; r < 4; ++r) pm = fmaxf(pm, sacc[i][j][r]);
      pm = fmaxf(pm, __shfl_xor(pm, 16));
      pm = fmaxf(pm, __shfl_xor(pm, 32));
      const float mn = fmaxf(m_reg[j], pm);
      alpha[j] = __expf(m_reg[j] - mn);
      float ps = 0.f;
#pragma unroll
      for (int i = 0; i < 8; ++i)
#pragma unroll
        for (int r = 0; r < 4; ++r) {
          float s = sacc[i][j][r];
          float pv = (s <= -1e29f) ? 0.f : __expf(s - mn);
          sacc[i][j][r] = pv;
          ps += pv;
        }
      ps += __shfl_xor(ps, 16);
      ps += __shfl_xor(ps, 32);
      l_reg[j] = alpha[j] * l_reg[j] + ps;
      m_reg[j] = mn;
    }
    // rescale accumulated O^T (cols = q)
#pragma unroll
    for (int i = 0; i < 8; ++i)
#pragma unroll
      for (int j = 0; j < 2; ++j)
#pragma unroll
        for (int r = 0; r < 4; ++r) acc[i][j][r] *= alpha[j];

    // ---- P -> Ps[q][s] (per-wave-disjoint rows, b64 writes) ----
#pragma unroll
    for (int j = 0; j < 2; ++j)
#pragma unroll
      for (int i = 0; i < 8; ++i) {
        ushort4 pk;
        pk.x = f2bf(sacc[i][j][0]); pk.y = f2bf(sacc[i][j][1]);
        pk.z = f2bf(sacc[i][j][2]); pk.w = f2bf(sacc[i][j][3]);
        *(ushort4*)&Ps[(wv * 32 + j * 16 + l15) * 136 + i * 16 + l4 * 4] = pk;
      }

    // [K] drain V(st), keep K(st+1) in flight
    if (pf) asm volatile("s_waitcnt vmcnt(8)" ::: "memory");
    else    asm volatile("s_waitcnt vmcnt(0)" ::: "memory");
    __builtin_amdgcn_s_barrier();   // [L] Vts visible
    asm volatile("" ::: "memory");

    // ---- PV: acc[i'][j] += V^T[d-tile i'] . P[q-tile j] ----
    __builtin_amdgcn_s_setprio(1);
#pragma unroll
    for (int ks = 0; ks < 4; ++ks) {
      const int co = ((((ks << 2) + l4) ^ e3) << 3);
      short8 af[8], bq[2];
#pragma unroll
      for (int i = 0; i < 8; ++i)
        af[i] = *(const short8*)(Vts + (i * 16 + l15) * 128 + co);
#pragma unroll
      for (int j = 0; j < 2; ++j)
        bq[j] = *(const short8*)(Ps + (wv * 32 + j * 16 + l15) * 136 + ks * 32 + l4 * 8);
#pragma unroll
      for (int i = 0; i < 8; ++i)
#pragma unroll
        for (int j = 0; j < 2; ++j)
          acc[i][j] = __builtin_amdgcn_mfma_f32_16x16x32_bf16(af[i], bq[j], acc[i][j], 0, 0, 0);
    }
    __builtin_amdgcn_s_setprio(0);
  }

  // ---- epilogue: normalize, stage to Ps[q][d], coalesced store ----
  float linv[2];
#pragma unroll
  for (int j = 0; j < 2; ++j) linv[j] = 1.f / l_reg[j];
#pragma unroll
  for (int j = 0; j < 2; ++j)
#pragma unroll
    for (int i = 0; i < 8; ++i) {
      ushort4 pk;
      pk.x = f2bf(acc[i][j][0] * linv[j]);
      pk.y = f2bf(acc[i][j][1] * linv[j]);
      pk.z = f2bf(acc[i][j][2] * linv[j]);
      pk.w = f2bf(acc[i][j][3] * linv[j]);
      *(ushort4*)&Ps[(wv * 32 + j * 16 + l15) * 136 + i * 16 + l4 * 4] = pk;
    }
  __syncthreads();
#pragma unroll
  for (int p = 0; p < 8; ++p) {
    int rw = p * 16 + (tid >> 4);
    int d0 = (tid & 15) * 8;
    *(ulonglong2*)(attn + (size_t)(t0 + rw) * D_DIM + h * DH_N + d0) =
        *(const ulonglong2*)(Ps + rw * 136 + d0);
  }
}

// ---------------------------------------------------------------------------
extern "C" void kernel_launch(void* const* d_in, const int* in_sizes, int n_in,
                              void* d_out, int out_size, void* d_ws, size_t ws_size,
                              hipStream_t stream) {
  (void)in_sizes; (void)n_in; (void)out_size; (void)ws_size;
  const float* x      = (const float*)d_in[0];
  const float* Wq_idx = (const float*)d_in[1];
  const float* Wk_idx = (const float*)d_in[2];
  const float* Ww_idx = (const float*)d_in[3];
  const float* Wq     = (const float*)d_in[4];
  const float* Wk     = (const float*)d_in[5];
  const float* Wv     = (const float*)d_in[6];
  const float* Wo     = (const float*)d_in[7];
  float* out = (float*)d_out;

  char* ws = (char*)d_ws;
  const size_t MB = 1ull << 20;
  float*    scores  = (float*)(ws);
  ushort_t* qkv_bf  = (ushort_t*)(ws);
  unsigned long long* maskbits = (unsigned long long*)(ws + 25 * MB + 512 * 1024);
  ushort_t* x_bf    = (ushort_t*)(ws + 26 * MB);
  ushort_t* Wcat_t  = (ushort_t*)(ws + 34 * MB);  // 3 x [2048][2048]
  ushort_t* vt_bf   = (ushort_t*)(ws + 34 * MB);
  ushort_t* attn_bf = (ushort_t*)(ws + 42 * MB);
  ushort_t* Wo_t    = (ushort_t*)(ws + 58 * MB);
  float*    qi      = (float*)(ws + 66 * MB);
  float*    ki      = (float*)(ws + 68 * MB);
  float*    wI      = (float*)(ws + 68 * MB + 512 * 1024);

  const dim3 blk(256);
  const dim3 tgrid(D_DIM / 32, D_DIM / 32);

  cast_bf16<<<dim3((D_DIM * T_DIM) / 1024), blk, 0, stream>>>(x, x_bf);
  cast_transpose<<<tgrid, blk, 0, stream>>>(Wq, Wcat_t, D_DIM, D_DIM);
  cast_transpose<<<tgrid, blk, 0, stream>>>(Wk, Wcat_t + (size_t)D_DIM * D_DIM, D_DIM, D_DIM);
  cast_transpose<<<tgrid, blk, 0, stream>>>(Wv, Wcat_t + (size_t)2 * D_DIM * D_DIM, D_DIM, D_DIM);
  cast_transpose<<<tgrid, blk, 0, stream>>>(Wo, Wo_t, D_DIM, D_DIM);

  // indexer path (fp32, fused projections; 32x32 single-wave tiles)
  idx_proj<<<dim3(11, T_DIM / 32), dim3(64), 0, stream>>>(x, Wq_idx, Wk_idx, Ww_idx, qi, ki, wI);
  idx_scores_rt<<<dim3(T_DIM / 64, T_DIM / 64), blk, 0, stream>>>(qi, ki, wI, scores);
  select_mask<<<dim3(T_DIM), blk, 0, stream>>>(scores, maskbits);

  // fused qkv projection: [2048][6144] = x_bf @ Wcat_t^T (8-phase 256^2 GEMM)
  gemm256_bt<<<dim3(3 * D_DIM / 256, T_DIM / 256), dim3(512), 0, stream>>>(
      x_bf, Wcat_t, qkv_bf, T_DIM, 3 * D_DIM, D_DIM);

  // v^T from strided v view (cols 4096..6143 of qkv) ; vt overwrites Wq_t
  transpose_bf<<<dim3(D_DIM / 64, T_DIM / 64), blk, 0, stream>>>(
      qkv_bf + 2 * D_DIM, vt_bf, 3 * D_DIM);

  // flash masked attention (q = qkv cols 0..2047, k = cols 2048..4095)
  flash_attn<<<dim3(T_DIM / 128, H_N), blk, 0, stream>>>(
      qkv_bf, qkv_bf + D_DIM, vt_bf, maskbits, attn_bf, 3 * D_DIM);

  // output projection -> f32
  gemm_bt<0><<<dim3(D_DIM / 128, T_DIM / 128), blk, 0, stream>>>(
      attn_bf, Wo_t, out, T_DIM, D_DIM, D_DIM);
}

// Round 6
// 493.954 us; speedup vs baseline: 1.2575x; 1.2575x over previous
//
#include <hip/hip_runtime.h>
#include <cstdint>
#include <cstddef>

#define T_DIM 2048
#define D_DIM 2048
#define HI_N 4
#define DI_N 64
#define H_N 16
#define DH_N 128
#define TOPK_N 512
#define NEG_F (-1e9f)
#define FA_NEG (-1e30f)

typedef __attribute__((ext_vector_type(8))) short short8;
typedef __attribute__((ext_vector_type(4))) float f32x4;
typedef unsigned short ushort_t;

__device__ __forceinline__ unsigned short f2bf(float f) {
  unsigned u = __float_as_uint(f);
  u += 0x7FFFu + ((u >> 16) & 1u);   // RNE
  return (unsigned short)(u >> 16);
}
__device__ __forceinline__ float bf2f(unsigned short b) {
  return __uint_as_float((unsigned)b << 16);
}

#define GLDS(g, l) __builtin_amdgcn_global_load_lds( \
    (const __attribute__((address_space(1))) unsigned int*)(g), \
    (__attribute__((address_space(3))) unsigned int*)(l), 16, 0, 0)

// Partial clone layout (floats): qi [2048][256] at 0, ki [2048][64] at 524288,
// wI [2048][4] at 655360; clone stride 663552 floats (2.654 MB).
#define IDXP_QI_F   524288
#define IDXP_KI_F   131072
#define IDXP_WI_F   8192
#define IDXP_STRIDE (IDXP_QI_F + IDXP_KI_F + IDXP_WI_F)   // 663552

// ---------------------------------------------------------------------------
// Fused indexer projections, K-split x4 (fp32). Grid (6, 32, 4): z = K chunk
// [z*512, z*512+512). Per-block microkernel identical to the proven 64x64
// 4x4/thread version; each chunk's per-output k-order is sequential.
// 768 blocks -> 3 blocks/CU (vs 192 -> 0.75): latency hiding via TLP.
// ---------------------------------------------------------------------------
__global__ __launch_bounds__(256) void idx_proj(const float* __restrict__ x,
                                                const float* __restrict__ Wq_idx,
                                                const float* __restrict__ Wk_idx,
                                                const float* __restrict__ Ww_idx,
                                                float* __restrict__ parts) {
  __shared__ float As[2][16][64];
  __shared__ float Bs[2][16][64];
  const int bm = blockIdx.y << 6;
  const int bn_id = blockIdx.x;
  const int kbeg = blockIdx.z << 9;          // 0,512,1024,1536
  const int kend = kbeg + 512;
  float* part = parts + (size_t)blockIdx.z * IDXP_STRIDE;
  const float* B; float* C; int ldB, cb, ncols;
  if (bn_id < 4)       { B = Wq_idx; C = part;             ldB = 256; cb = bn_id << 6; ncols = 64; }
  else if (bn_id == 4) { B = Wk_idx; C = part + IDXP_QI_F; ldB = 64;  cb = 0;          ncols = 64; }
  else                 { B = Ww_idx; C = part + IDXP_QI_F + IDXP_KI_F; ldB = 4; cb = 0; ncols = 4; }
  const int tid = threadIdx.x;
  const int tx = tid & 15, ty = tid >> 4;
  const int am = tid >> 2;          // 0..63
  const int ak = (tid & 3) << 2;    // 0,4,8,12
  float acc[4][4] = {};

  // prologue: load + stage k0=kbeg into buf 0
  float4 a4 = *(const float4*)&x[(size_t)(bm + am) * 2048 + kbeg + ak];
  float4 b4 = make_float4(0, 0, 0, 0);
  if ((tx << 2) < ncols) b4 = *(const float4*)&B[(size_t)(kbeg + ty) * ldB + cb + (tx << 2)];
  As[0][ak + 0][am] = a4.x; As[0][ak + 1][am] = a4.y;
  As[0][ak + 2][am] = a4.z; As[0][ak + 3][am] = a4.w;
  *(float4*)&Bs[0][ty][tx << 2] = b4;

  int p = 0;
  for (int k0 = kbeg; k0 < kend; k0 += 16) {
    __syncthreads();  // buf p writes visible
    const bool more = (k0 + 16) < kend;
    if (more) {
      a4 = *(const float4*)&x[(size_t)(bm + am) * 2048 + k0 + 16 + ak];
      if ((tx << 2) < ncols)
        b4 = *(const float4*)&B[(size_t)(k0 + 16 + ty) * ldB + cb + (tx << 2)];
    }
#pragma unroll
    for (int kk = 0; kk < 16; ++kk) {
      float4 av4 = *(const float4*)&As[p][kk][ty << 2];
      float4 bv4 = *(const float4*)&Bs[p][kk][tx << 2];
      float av[4] = {av4.x, av4.y, av4.z, av4.w};
      float bv[4] = {bv4.x, bv4.y, bv4.z, bv4.w};
#pragma unroll
      for (int i = 0; i < 4; ++i)
#pragma unroll
        for (int j = 0; j < 4; ++j) acc[i][j] += av[i] * bv[j];
    }
    if (more) {
      As[1 - p][ak + 0][am] = a4.x; As[1 - p][ak + 1][am] = a4.y;
      As[1 - p][ak + 2][am] = a4.z; As[1 - p][ak + 3][am] = a4.w;
      *(float4*)&Bs[1 - p][ty][tx << 2] = b4;
    }
    p ^= 1;
  }
#pragma unroll
  for (int i = 0; i < 4; ++i) {
    int m = bm + (ty << 2) + i;
    int n0 = tx << 2;
    if (n0 + 3 < ncols) {
      *(float4*)&C[(size_t)m * ldB + cb + n0] =
          make_float4(acc[i][0], acc[i][1], acc[i][2], acc[i][3]);
    } else {
#pragma unroll
      for (int j = 0; j < 4; ++j)
        if (n0 + j < ncols) C[(size_t)m * ldB + cb + n0 + j] = acc[i][j];
    }
  }
}

// Reduce 4 partial clones: dst = ((p0+p1)+p2)+p3, elementwise (float4).
__global__ __launch_bounds__(256) void idx_reduce(const float* __restrict__ parts,
                                                  float* __restrict__ qi,
                                                  float* __restrict__ ki,
                                                  float* __restrict__ wI) {
  const size_t f = ((size_t)blockIdx.x * 256 + threadIdx.x) * 4;
  float4 r0 = *(const float4*)(parts + f);
  float4 r1 = *(const float4*)(parts + (size_t)IDXP_STRIDE + f);
  float4 r2 = *(const float4*)(parts + (size_t)2 * IDXP_STRIDE + f);
  float4 r3 = *(const float4*)(parts + (size_t)3 * IDXP_STRIDE + f);
  float4 r;
  r.x = ((r0.x + r1.x) + r2.x) + r3.x;
  r.y = ((r0.y + r1.y) + r2.y) + r3.y;
  r.z = ((r0.z + r1.z) + r2.z) + r3.z;
  r.w = ((r0.w + r1.w) + r2.w) + r3.w;
  float* dst;
  if (f < IDXP_QI_F)                     dst = qi + f;
  else if (f < IDXP_QI_F + IDXP_KI_F)    dst = ki + (f - IDXP_QI_F);
  else                                   dst = wI + (f - IDXP_QI_F - IDXP_KI_F);
  *(float4*)dst = r;
}

// ---------------------------------------------------------------------------
// casts / transposes
// ---------------------------------------------------------------------------
__global__ __launch_bounds__(256) void cast_bf16(const float* __restrict__ in,
                                                 ushort_t* __restrict__ out) {
  int i = (blockIdx.x * 256 + threadIdx.x) * 4;
  float4 f = *(const float4*)(in + i);
  ushort4 o;
  o.x = f2bf(f.x); o.y = f2bf(f.y); o.z = f2bf(f.z); o.w = f2bf(f.w);
  *(ushort4*)(out + i) = o;
}

// in[R][C] f32 -> out[C][R] bf16
__global__ __launch_bounds__(256) void cast_transpose(const float* __restrict__ in,
                                                      ushort_t* __restrict__ out,
                                                      int R, int C) {
  __shared__ float tile[32][33];
  const int bx = blockIdx.x * 32;
  const int by = blockIdx.y * 32;
  const int tx = threadIdx.x & 31, ty = threadIdx.x >> 5;
#pragma unroll
  for (int i = 0; i < 32; i += 8)
    tile[ty + i][tx] = in[(size_t)(by + ty + i) * C + bx + tx];
  __syncthreads();
#pragma unroll
  for (int i = 0; i < 32; i += 8)
    out[(size_t)(bx + ty + i) * R + by + tx] = f2bf(tile[tx][ty + i]);
}

// bf16 [T][ldin] -> [C][T] (transpose 64x64 tiles), ldin-strided input
__global__ __launch_bounds__(256) void transpose_bf(const ushort_t* __restrict__ in,
                                                    ushort_t* __restrict__ out,
                                                    int ldin) {
  __shared__ ushort_t tile[64][68];
  const int bx = blockIdx.x * 64;  // col base (input)
  const int by = blockIdx.y * 64;  // row base (input)
  const int tid = threadIdx.x;
#pragma unroll
  for (int p = 0; p < 4; ++p) {
    int r = p * 16 + (tid >> 4), c0 = (tid & 15) * 4;
    *(ushort4*)&tile[r][c0] = *(const ushort4*)(in + (size_t)(by + r) * ldin + bx + c0);
  }
  __syncthreads();
#pragma unroll
  for (int p = 0; p < 4; ++p) {
    int r = p * 16 + (tid >> 4), c0 = (tid & 15) * 4;
    ushort4 o;
    o.x = tile[c0 + 0][r]; o.y = tile[c0 + 1][r];
    o.z = tile[c0 + 2][r]; o.w = tile[c0 + 3][r];
    *(ushort4*)(out + (size_t)(bx + r) * T_DIM + by + c0) = o;
  }
}

// ---------------------------------------------------------------------------
// bf16 MFMA GEMM: C[M,N] = A[M,K] @ Bt[N,K]^T (m97 128^2 structure; used for Wo)
// ---------------------------------------------------------------------------
template <int OUT_BF16>
__global__ __launch_bounds__(256) void gemm_bt(const ushort_t* __restrict__ A,
                                               const ushort_t* __restrict__ Bt,
                                               void* __restrict__ C,
                                               int M, int N, int K) {
  __shared__ __attribute__((aligned(16))) ushort_t As[128 * 64];
  __shared__ __attribute__((aligned(16))) ushort_t Bs[128 * 64];
  const int bm = blockIdx.y << 7;
  const int bn = blockIdx.x << 7;
  const int tid = threadIdx.x;
  const int lane = tid & 63;
  const int wv = tid >> 6;
  const int wm = (wv >> 1) << 6;
  const int wn = (wv & 1) << 6;

  f32x4 acc[4][4] = {};

  const int sr = tid >> 3;
  const int sc = (tid & 7) << 3;
  const ushort_t* ga = A + (size_t)(bm + sr) * K + sc;
  const ushort_t* gb = Bt + (size_t)(bn + sr) * K + sc;
  const size_t rstep = (size_t)32 * K;

  for (int k0 = 0; k0 < K; k0 += 64) {
#pragma unroll
    for (int i = 0; i < 4; ++i) {
      GLDS(ga + i * rstep + k0, As + i * 2048 + tid * 8);
      GLDS(gb + i * rstep + k0, Bs + i * 2048 + tid * 8);
    }
    __syncthreads();
#pragma unroll
    for (int ks = 0; ks < 2; ++ks) {
      short8 af[4], bfr[4];
      const int kk = (ks << 5) + ((lane >> 4) << 3);
#pragma unroll
      for (int i = 0; i < 4; ++i) {
        af[i]  = *(const short8*)(As + (wm + (i << 4) + (lane & 15)) * 64 + kk);
        bfr[i] = *(const short8*)(Bs + (wn + (i << 4) + (lane & 15)) * 64 + kk);
      }
#pragma unroll
      for (int i = 0; i < 4; ++i)
#pragma unroll
        for (int j = 0; j < 4; ++j)
          acc[i][j] = __builtin_amdgcn_mfma_f32_16x16x32_bf16(af[i], bfr[j], acc[i][j], 0, 0, 0);
    }
    __syncthreads();
  }

  const int lrow = (lane >> 4) << 2;
  const int lcol = lane & 15;
#pragma unroll
  for (int i = 0; i < 4; ++i) {
    const int row = bm + wm + (i << 4) + lrow;
#pragma unroll
    for (int j = 0; j < 4; ++j) {
      const int col = bn + wn + (j << 4) + lcol;
#pragma unroll
      for (int r = 0; r < 4; ++r) {
        if (OUT_BF16)
          ((ushort_t*)C)[(size_t)(row + r) * N + col] = f2bf(acc[i][j][r]);
        else
          ((float*)C)[(size_t)(row + r) * N + col] = acc[i][j][r];
      }
    }
  }
}

// ---------------------------------------------------------------------------
// 256x256-tile 8-phase bf16 GEMM (T2+T3+T4+T5), C bf16 = A[M,K] @ Bt[N,K]^T.
// ---------------------------------------------------------------------------
__global__ __launch_bounds__(512, 2) void gemm256_bt(const ushort_t* __restrict__ A,
                                                     const ushort_t* __restrict__ Bt,
                                                     ushort_t* __restrict__ C,
                                                     int M, int N, int K) {
  __shared__ __attribute__((aligned(16))) ushort_t Ab[2][256 * 64];
  __shared__ __attribute__((aligned(16))) ushort_t Bb[2][256 * 64];
  const int bm = blockIdx.y << 8;
  const int bn = blockIdx.x << 8;
  const int tid = threadIdx.x;
  const int lane = tid & 63;
  const int wid = tid >> 6;
  const int wr = wid >> 2;          // 0..1  (M half)
  const int wc = wid & 3;           // 0..3  (N quarter)
  const int l15 = lane & 15, l4 = lane >> 4;
  const int srow = tid >> 3;        // 0..63
  const int schunk = tid & 7;
  const int swc = (schunk ^ (srow & 7)) << 3;   // pre-swizzled source col
  const int NT = K >> 6;

  f32x4 acc[8][4] = {};

#define STAGE_A(b, h, kt) { \
    const ushort_t* g_ = A + (size_t)(bm + (h) * 64 + srow) * K + (kt) * 64 + swc; \
    GLDS(g_, Ab[b] + ((h) * 64 + srow) * 64 + (schunk << 3)); \
    GLDS(g_ + (size_t)128 * K, Ab[b] + (128 + (h) * 64 + srow) * 64 + (schunk << 3)); }

#define STAGE_B(b, h, kt) { \
    const int br_ = ((srow >= 32) ? 64 : 0) + (h) * 32 + (srow & 31); \
    const ushort_t* g_ = Bt + (size_t)(bn + br_) * K + (kt) * 64 + swc; \
    GLDS(g_, Bb[b] + br_ * 64 + (schunk << 3)); \
    GLDS(g_ + (size_t)128 * K, Bb[b] + (128 + br_) * 64 + (schunk << 3)); }

#define VMW(n) asm volatile("s_waitcnt vmcnt(" #n ")" ::: "memory")

#define PHASE(b, qm, qn, STG, WT) { \
    short8 paf[4][2], pbf[2][2]; \
    _Pragma("unroll") for (int m_ = 0; m_ < 4; ++m_) { \
      const int Ra_ = wr * 128 + (qm) * 64 + m_ * 16 + l15; \
      _Pragma("unroll") for (int ks_ = 0; ks_ < 2; ++ks_) \
        paf[m_][ks_] = *(const short8*)(Ab[b] + Ra_ * 64 + ((((ks_ << 2) + l4) ^ (Ra_ & 7)) << 3)); } \
    _Pragma("unroll") for (int n_ = 0; n_ < 2; ++n_) { \
      const int Rb_ = wc * 64 + (qn) * 32 + n_ * 16 + l15; \
      _Pragma("unroll") for (int ks_ = 0; ks_ < 2; ++ks_) \
        pbf[n_][ks_] = *(const short8*)(Bb[b] + Rb_ * 64 + ((((ks_ << 2) + l4) ^ (Rb_ & 7)) << 3)); } \
    STG; \
    WT; \
    asm volatile("" ::: "memory"); \
    __builtin_amdgcn_s_barrier(); \
    asm volatile("s_waitcnt lgkmcnt(0)" ::: "memory"); \
    __builtin_amdgcn_sched_barrier(0); \
    __builtin_amdgcn_s_setprio(1); \
    _Pragma("unroll") for (int m_ = 0; m_ < 4; ++m_) \
      _Pragma("unroll") for (int n_ = 0; n_ < 2; ++n_) \
        _Pragma("unroll") for (int ks_ = 0; ks_ < 2; ++ks_) \
          acc[(qm) * 4 + m_][(qn) * 2 + n_] = __builtin_amdgcn_mfma_f32_16x16x32_bf16( \
              paf[m_][ks_], pbf[n_][ks_], acc[(qm) * 4 + m_][(qn) * 2 + n_], 0, 0, 0); \
    __builtin_amdgcn_s_setprio(0); \
    asm volatile("" ::: "memory"); \
    __builtin_amdgcn_s_barrier(); \
    asm volatile("" ::: "memory"); }

  // prologue = virtual P3..P8: tile0 all 4 halves -> b0; tile1 ev halves -> b1
  STAGE_A(0, 0, 0); STAGE_B(0, 0, 0); STAGE_A(0, 1, 0); STAGE_B(0, 1, 0);
  STAGE_A(1, 0, 1); STAGE_B(1, 0, 1);
  VMW(8);                      // confirms b0 A-ev, B-ev
  asm volatile("" ::: "memory");
  __builtin_amdgcn_s_barrier();
  asm volatile("" ::: "memory");

  for (int j = 0; j < NT / 2 - 1; ++j) {
    const int t = j * 2;
    PHASE(0, 0, 0, STAGE_A(1, 1, t + 1), VMW(6));   // confirms thru b0 B-od
    PHASE(0, 0, 1, STAGE_B(1, 1, t + 1), );
    PHASE(0, 1, 0, STAGE_A(0, 0, t + 2), );
    PHASE(0, 1, 1, STAGE_B(0, 0, t + 2), VMW(8));   // confirms thru b1 ev
    PHASE(1, 0, 0, STAGE_A(0, 1, t + 2), VMW(6));   // confirms thru b1 B-od
    PHASE(1, 0, 1, STAGE_B(0, 1, t + 2), );
    PHASE(1, 1, 0, STAGE_A(1, 0, t + 3), );
    PHASE(1, 1, 1, STAGE_B(1, 0, t + 3), VMW(8));   // confirms thru b0 ev
  }
  // tail: tiles NT-2 (b0, fully staged), NT-1 (b1: ev staged, od staged here)
  PHASE(0, 0, 0, STAGE_A(1, 1, NT - 1), VMW(6));
  PHASE(0, 0, 1, STAGE_B(1, 1, NT - 1), );
  PHASE(0, 1, 0, , );
  PHASE(0, 1, 1, , VMW(4));    // confirms b1 ev
  PHASE(1, 0, 0, , VMW(0));    // confirms b1 od
  PHASE(1, 0, 1, , );
  PHASE(1, 1, 0, , );
  PHASE(1, 1, 1, , );

#undef STAGE_A
#undef STAGE_B
#undef VMW
#undef PHASE

  // epilogue
#pragma unroll
  for (int i = 0; i < 8; ++i) {
    const int row = bm + wr * 128 + i * 16 + l4 * 4;
#pragma unroll
    for (int j2 = 0; j2 < 4; ++j2) {
      const int col = bn + wc * 64 + j2 * 16 + l15;
#pragma unroll
      for (int r = 0; r < 4; ++r)
        C[(size_t)(row + r) * N + col] = f2bf(acc[i][j2][r]);
    }
  }
}

// ---------------------------------------------------------------------------
// Lightning indexer scores, register-tiled 64x64 fp32
// ---------------------------------------------------------------------------
__global__ __launch_bounds__(256) void idx_scores_rt(const float* __restrict__ qi,
                                                     const float* __restrict__ ki,
                                                     const float* __restrict__ w,
                                                     float* __restrict__ out) {
  const int t0 = blockIdx.y << 6, s0 = blockIdx.x << 6;
  const int tid = threadIdx.x;
  const int tx = tid & 15, ty = tid >> 4;
  if (s0 > t0 + 63) {  // fully above diagonal: NEG fill (ws is poisoned!)
    const float4 nf = make_float4(NEG_F, NEG_F, NEG_F, NEG_F);
#pragma unroll
    for (int i = 0; i < 4; ++i) {
      int m = t0 + (ty << 2) + i;
      *(float4*)&out[(size_t)m * T_DIM + s0 + (tx << 2)] = nf;
    }
    return;
  }
  __shared__ float As[16][64];   // [kk][t]
  __shared__ float Bs[16][64];   // [kk][s]
  __shared__ float wsh[64][4];
  if (tid < 64) *(float4*)wsh[tid] = *(const float4*)&w[(size_t)(t0 + tid) * 4];
  const int am = tid >> 2;          // 0..63
  const int ak = (tid & 3) << 2;    // 0,4,8,12
  float oacc[4][4] = {};
#pragma unroll
  for (int h = 0; h < HI_N; ++h) {
    float dacc[4][4] = {};
    for (int k0 = 0; k0 < DI_N; k0 += 16) {
      float4 qa = *(const float4*)&qi[(size_t)(t0 + am) * 256 + h * DI_N + k0 + ak];
      float4 kb = *(const float4*)&ki[(size_t)(s0 + am) * DI_N + k0 + ak];
      __syncthreads();
      As[ak + 0][am] = qa.x; As[ak + 1][am] = qa.y;
      As[ak + 2][am] = qa.z; As[ak + 3][am] = qa.w;
      Bs[ak + 0][am] = kb.x; Bs[ak + 1][am] = kb.y;
      Bs[ak + 2][am] = kb.z; Bs[ak + 3][am] = kb.w;
      __syncthreads();
#pragma unroll
      for (int kk = 0; kk < 16; ++kk) {
        float4 a4 = *(const float4*)&As[kk][ty << 2];
        float4 b4 = *(const float4*)&Bs[kk][tx << 2];
        float av[4] = {a4.x, a4.y, a4.z, a4.w};
        float bv[4] = {b4.x, b4.y, b4.z, b4.w};
#pragma unroll
        for (int i = 0; i < 4; ++i)
#pragma unroll
          for (int j = 0; j < 4; ++j) dacc[i][j] += av[i] * bv[j];
      }
    }
#pragma unroll
    for (int i = 0; i < 4; ++i) {
      float wh = wsh[(ty << 2) + i][h];
#pragma unroll
      for (int j = 0; j < 4; ++j) oacc[i][j] += fmaxf(dacc[i][j], 0.f) * wh;
    }
  }
#pragma unroll
  for (int i = 0; i < 4; ++i) {
    int m = t0 + (ty << 2) + i;
    int n0 = s0 + (tx << 2);
    float4 r;
    r.x = (n0 + 0 > m) ? NEG_F : oacc[i][0];
    r.y = (n0 + 1 > m) ? NEG_F : oacc[i][1];
    r.z = (n0 + 2 > m) ? NEG_F : oacc[i][2];
    r.w = (n0 + 3 > m) ? NEG_F : oacc[i][3];
    *(float4*)&out[(size_t)m * T_DIM + n0] = r;
  }
}

// ---------------------------------------------------------------------------
// Per-row top-512 -> bitmask. Radix-histogram select, jax tie semantics.
// ---------------------------------------------------------------------------
__global__ __launch_bounds__(256) void select_mask(const float* __restrict__ scores,
                                                   unsigned long long* __restrict__ maskbits) {
  const int t = blockIdx.x, tid = threadIdx.x;
  __shared__ unsigned int hist[256];
  __shared__ unsigned int s_prefix, s_krem;
  __shared__ unsigned char bytes[256];
  unsigned int uv[8];
  const float* row = scores + (size_t)t * T_DIM;
  {
    float4 f0 = *(const float4*)(row + tid * 8);
    float4 f1 = *(const float4*)(row + tid * 8 + 4);
    float fv[8] = {f0.x, f0.y, f0.z, f0.w, f1.x, f1.y, f1.z, f1.w};
#pragma unroll
    for (int j = 0; j < 8; ++j) {
      unsigned u = __float_as_uint(fv[j]);
      uv[j] = (u & 0x80000000u) ? ~u : (u | 0x80000000u);
    }
  }
  if (tid == 0) { s_prefix = 0u; s_krem = TOPK_N; }
  for (int p = 0; p < 4; ++p) {
    const int sh = 24 - 8 * p;
    hist[tid] = 0;
    __syncthreads();
    const unsigned pm = p ? (0xFFFFFFFFu << (32 - 8 * p)) : 0u;
    const unsigned prefix = s_prefix;
#pragma unroll
    for (int j = 0; j < 8; ++j)
      if ((uv[j] & pm) == prefix) atomicAdd(&hist[(uv[j] >> sh) & 255], 1u);
    __syncthreads();
    if (tid == 0) {
      unsigned krem = s_krem, cum = 0;
      int b = 255;
      for (;; --b) { cum += hist[b]; if (cum >= krem) break; }
      s_prefix = prefix | ((unsigned)b << sh);
      s_krem = krem - (cum - hist[b]);
    }
    __syncthreads();
  }
  const unsigned V = s_prefix;
  const int kr = (int)s_krem;
  int eqc = 0;
#pragma unroll
  for (int j = 0; j < 8; ++j) eqc += (uv[j] == V);
  __syncthreads();
  hist[tid] = (unsigned)eqc;
  __syncthreads();
  for (int off = 1; off < 256; off <<= 1) {
    int v = (int)hist[tid];
    if (tid >= off) v += (int)hist[tid - off];
    __syncthreads();
    hist[tid] = (unsigned)v;
    __syncthreads();
  }
  int run = (int)hist[tid] - eqc;
  unsigned char byte = 0;
#pragma unroll
  for (int j = 0; j < 8; ++j) {
    bool eq = (uv[j] == V);
    bool take = (uv[j] > V) || (eq && run < kr);
    run += eq;
    byte |= (unsigned char)(take ? (1u << j) : 0u);
  }
  bytes[tid] = byte;
  __syncthreads();
  if (tid < 32) {
    unsigned long long wqw = 0;
#pragma unroll
    for (int b = 0; b < 8; ++b)
      wqw |= (unsigned long long)bytes[tid * 8 + b] << (8 * b);
    maskbits[(size_t)t * 32 + tid] = wqw;
  }
}

// ---------------------------------------------------------------------------
// Flash masked attention (bf16 MFMA), SWAPPED-operand QK^T.
// ---------------------------------------------------------------------------
__global__ __launch_bounds__(256, 1) void flash_attn(
    const ushort_t* __restrict__ q, const ushort_t* __restrict__ k,
    const ushort_t* __restrict__ vt, const unsigned long long* __restrict__ maskbits,
    ushort_t* __restrict__ attn, int ldqk) {
  __shared__ __attribute__((aligned(16))) ushort_t Ks[2][128 * 128];
  __shared__ __attribute__((aligned(16))) ushort_t Vts[128 * 128];
  __shared__ __attribute__((aligned(16))) ushort_t Ps[128 * 136];

  const int tt = blockIdx.x;
  const int h  = blockIdx.y;
  const int t0 = tt << 7;
  const int tid = threadIdx.x;
  const int lane = tid & 63;
  const int wv = tid >> 6;              // wave id; owns q rows [wv*32, +32)
  const int l15 = lane & 15, l4 = lane >> 4;
  const int e3 = l15 & 7;                                  // read-side swizzle
  const int scol = (((tid & 15) ^ ((tid >> 4) & 7)) << 3); // staging source col

  // ---- stage Q (inverse-swizzled source) into Ks[0], read q fragments ----
  {
    const ushort_t* gq = q + (size_t)(t0 + (tid >> 4)) * ldqk + h * DH_N + scol;
#pragma unroll
    for (int p = 0; p < 8; ++p)
      GLDS(gq + (size_t)p * 16 * ldqk, Ks[0] + p * 2048 + tid * 8);
  }
  asm volatile("s_waitcnt vmcnt(0)" ::: "memory");
  __builtin_amdgcn_s_barrier();
  asm volatile("" ::: "memory");
  short8 qfrag[4][2];   // [ks][j]: Q rows wv*32 + j*16 + l15
#pragma unroll
  for (int ks = 0; ks < 4; ++ks)
#pragma unroll
    for (int j = 0; j < 2; ++j)
      qfrag[ks][j] = *(const short8*)(Ks[0] + (wv * 32 + j * 16 + l15) * 128 +
                                      ((((ks << 2) + l4) ^ e3) << 3));
  asm volatile("s_waitcnt lgkmcnt(0)" ::: "memory");
  __builtin_amdgcn_s_barrier();
  asm volatile("" ::: "memory");

  f32x4 acc[8][2] = {};              // O^T: [d-tile][q-tile]
  float m_reg[2] = {-INFINITY, -INFINITY};
  float l_reg[2] = {0.f, 0.f};
  const int nst = (tt < 4) ? 4 : (tt + 1);
  const float rsc = 0.08838834764831845f;  // 1/sqrt(128)

  // issue K(0) into Ks[0] (overwrites Q staging; qfrag already in registers)
  {
    const ushort_t* gk = k + (size_t)(tid >> 4) * ldqk + h * DH_N + scol;
#pragma unroll
    for (int p = 0; p < 8; ++p)
      GLDS(gk + (size_t)p * 16 * ldqk, Ks[0] + p * 2048 + tid * 8);
  }

  for (int st = 0; st < nst; ++st) {
    const int s0 = st << 7;
    const bool pf = (st + 1) < nst;

    // [A] all waves done with PV of st-1 -> Vts free for overwrite
    asm volatile("" ::: "memory");
    __builtin_amdgcn_s_barrier();
    asm volatile("" ::: "memory");

    // [B] mask words (4/lane)
    unsigned long long mw[2][2];
    {
      const int wbase = s0 >> 6;
#pragma unroll
      for (int j = 0; j < 2; ++j)
#pragma unroll
        for (int wd = 0; wd < 2; ++wd)
          mw[j][wd] = maskbits[(size_t)(t0 + wv * 32 + j * 16 + l15) * 32 + wbase + wd];
    }
    // [C] V(st) -> Vts (8 loads); consumed in PV (latency hidden)
    {
      const ushort_t* gv = vt + (size_t)(h * DH_N + (tid >> 4)) * T_DIM + s0 + scol;
#pragma unroll
      for (int p = 0; p < 8; ++p)
        GLDS(gv + (size_t)p * 16 * T_DIM, Vts + p * 2048 + tid * 8);
    }
    asm volatile("" ::: "memory");  // order: V strictly before K-prefetch
    // [D] K(st+1) prefetch into other buffer (8 loads)
    if (pf) {
      const ushort_t* gk = k + (size_t)(s0 + 128 + (tid >> 4)) * ldqk + h * DH_N + scol;
      ushort_t* dst = Ks[(st + 1) & 1];
#pragma unroll
      for (int p = 0; p < 8; ++p)
        GLDS(gk + (size_t)p * 16 * ldqk, dst + p * 2048 + tid * 8);
    }
    // [E] drain K(st) only: 4(mask)+8(V)+8(K+1) newer ops stay in flight
    if (pf) asm volatile("s_waitcnt vmcnt(20)" ::: "memory");
    else    asm volatile("s_waitcnt vmcnt(12)" ::: "memory");
    __builtin_amdgcn_s_barrier();   // [F] K(st) visible to all waves
    asm volatile("" ::: "memory");

    // ---- QK^T (swapped): sacc[i][j] rows = s, cols = q ----
    const ushort_t* Kb = Ks[st & 1];
    f32x4 sacc[8][2] = {};
    __builtin_amdgcn_s_setprio(1);
#pragma unroll
    for (int ks = 0; ks < 4; ++ks) {
      const int co = ((((ks << 2) + l4) ^ e3) << 3);
      short8 af[8];
#pragma unroll
      for (int i = 0; i < 8; ++i)
        af[i] = *(const short8*)(Kb + (i * 16 + l15) * 128 + co);
#pragma unroll
      for (int i = 0; i < 8; ++i)
#pragma unroll
        for (int j = 0; j < 2; ++j)
          sacc[i][j] = __builtin_amdgcn_mfma_f32_16x16x32_bf16(af[i], qfrag[ks][j], sacc[i][j], 0, 0, 0);
    }
    __builtin_amdgcn_s_setprio(0);

    // ---- mask + scale: s = i*16 + l4*4 + r ----
#pragma unroll
    for (int i = 0; i < 8; ++i)
#pragma unroll
      for (int j = 0; j < 2; ++j)
#pragma unroll
        for (int r = 0; r < 4; ++r) {
          bool sel = (mw[j][i >> 2] >> ((i & 3) * 16 + l4 * 4 + r)) & 1;
          sacc[i][j][r] = sel ? sacc[i][j][r] * rsc : FA_NEG;
        }

    // ---- in-register online softmax (per q column j) ----
    float alpha[2];
#pragma unroll
    for (int j = 0; j < 2; ++j) {
      float pm = sacc[0][j][0];
#pragma unroll
      for (int i = 0; i < 8; ++i)
#pragma unroll
        for (int r = 0; r < 4; ++r) pm = fmaxf(pm, sacc[i][j][r]);
      pm = fmaxf(pm, __shfl_xor(pm, 16));
      pm = fmaxf(pm, __shfl_xor(pm, 32));
      const float mn = fmaxf(m_reg[j], pm);
      alpha[j] = __expf(m_reg[j] - mn);
      float ps = 0.f;
#pragma unroll
      for (int i = 0; i < 8; ++i)
#pragma unroll
        for (int r = 0; r < 4; ++r) {
          float s = sacc[i][j][r];
          float pv = (s <= -1e29f) ? 0.f : __expf(s - mn);
          sacc[i][j][r] = pv;
          ps += pv;
        }
      ps += __shfl_xor(ps, 16);
      ps += __shfl_xor(ps, 32);
      l_reg[j] = alpha[j] * l_reg[j] + ps;
      m_reg[j] = mn;
    }
    // rescale accumulated O^T (cols = q)
#pragma unroll
    for (int i = 0; i < 8; ++i)
#pragma unroll
      for (int j = 0; j < 2; ++j)
#pragma unroll
        for (int r = 0; r < 4; ++r) acc[i][j][r] *= alpha[j];

    // ---- P -> Ps[q][s] (per-wave-disjoint rows, b64 writes) ----
#pragma unroll
    for (int j = 0; j < 2; ++j)
#pragma unroll
      for (int i = 0; i < 8; ++i) {
        ushort4 pk;
        pk.x = f2bf(sacc[i][j][0]); pk.y = f2bf(sacc[i][j][1]);
        pk.z = f2bf(sacc[i][j][2]); pk.w = f2bf(sacc[i][j][3]);
        *(ushort4*)&Ps[(wv * 32 + j * 16 + l15) * 136 + i * 16 + l4 * 4] = pk;
      }

    // [K] drain V(st), keep K(st+1) in flight
    if (pf) asm volatile("s_waitcnt vmcnt(8)" ::: "memory");
    else    asm volatile("s_waitcnt vmcnt(0)" ::: "memory");
    __builtin_amdgcn_s_barrier();   // [L] Vts visible
    asm volatile("" ::: "memory");

    // ---- PV: acc[i'][j] += V^T[d-tile i'] . P[q-tile j] ----
    __builtin_amdgcn_s_setprio(1);
#pragma unroll
    for (int ks = 0; ks < 4; ++ks) {
      const int co = ((((ks << 2) + l4) ^ e3) << 3);
      short8 af[8], bq[2];
#pragma unroll
      for (int i = 0; i < 8; ++i)
        af[i] = *(const short8*)(Vts + (i * 16 + l15) * 128 + co);
#pragma unroll
      for (int j = 0; j < 2; ++j)
        bq[j] = *(const short8*)(Ps + (wv * 32 + j * 16 + l15) * 136 + ks * 32 + l4 * 8);
#pragma unroll
      for (int i = 0; i < 8; ++i)
#pragma unroll
        for (int j = 0; j < 2; ++j)
          acc[i][j] = __builtin_amdgcn_mfma_f32_16x16x32_bf16(af[i], bq[j], acc[i][j], 0, 0, 0);
    }
    __builtin_amdgcn_s_setprio(0);
  }

  // ---- epilogue: normalize, stage to Ps[q][d], coalesced store ----
  float linv[2];
#pragma unroll
  for (int j = 0; j < 2; ++j) linv[j] = 1.f / l_reg[j];
#pragma unroll
  for (int j = 0; j < 2; ++j)
#pragma unroll
    for (int i = 0; i < 8; ++i) {
      ushort4 pk;
      pk.x = f2bf(acc[i][j][0] * linv[j]);
      pk.y = f2bf(acc[i][j][1] * linv[j]);
      pk.z = f2bf(acc[i][j][2] * linv[j]);
      pk.w = f2bf(acc[i][j][3] * linv[j]);
      *(ushort4*)&Ps[(wv * 32 + j * 16 + l15) * 136 + i * 16 + l4 * 4] = pk;
    }
  __syncthreads();
#pragma unroll
  for (int p = 0; p < 8; ++p) {
    int rw = p * 16 + (tid >> 4);
    int d0 = (tid & 15) * 8;
    *(ulonglong2*)(attn + (size_t)(t0 + rw) * D_DIM + h * DH_N + d0) =
        *(const ulonglong2*)(Ps + rw * 136 + d0);
  }
}

// ---------------------------------------------------------------------------
extern "C" void kernel_launch(void* const* d_in, const int* in_sizes, int n_in,
                              void* d_out, int out_size, void* d_ws, size_t ws_size,
                              hipStream_t stream) {
  (void)in_sizes; (void)n_in; (void)out_size; (void)ws_size;
  const float* x      = (const float*)d_in[0];
  const float* Wq_idx = (const float*)d_in[1];
  const float* Wk_idx = (const float*)d_in[2];
  const float* Ww_idx = (const float*)d_in[3];
  const float* Wq     = (const float*)d_in[4];
  const float* Wk     = (const float*)d_in[5];
  const float* Wv     = (const float*)d_in[6];
  const float* Wo     = (const float*)d_in[7];
  float* out = (float*)d_out;

  char* ws = (char*)d_ws;
  const size_t MB = 1ull << 20;
  // layout: [0,10.7) idx partials (transient) -> scores f32 [0,16) -> qkv_bf
  float*    parts   = (float*)(ws);
  float*    scores  = (float*)(ws);
  ushort_t* qkv_bf  = (ushort_t*)(ws);
  unsigned long long* maskbits = (unsigned long long*)(ws + 25 * MB + 512 * 1024);
  ushort_t* x_bf    = (ushort_t*)(ws + 26 * MB);
  ushort_t* Wcat_t  = (ushort_t*)(ws + 34 * MB);  // 3 x [2048][2048]
  ushort_t* vt_bf   = (ushort_t*)(ws + 34 * MB);
  ushort_t* attn_bf = (ushort_t*)(ws + 42 * MB);
  ushort_t* Wo_t    = (ushort_t*)(ws + 58 * MB);
  float*    qi      = (float*)(ws + 66 * MB);
  float*    ki      = (float*)(ws + 68 * MB);
  float*    wI      = (float*)(ws + 68 * MB + 512 * 1024);

  const dim3 blk(256);
  const dim3 tgrid(D_DIM / 32, D_DIM / 32);

  cast_bf16<<<dim3((D_DIM * T_DIM) / 1024), blk, 0, stream>>>(x, x_bf);
  cast_transpose<<<tgrid, blk, 0, stream>>>(Wq, Wcat_t, D_DIM, D_DIM);
  cast_transpose<<<tgrid, blk, 0, stream>>>(Wk, Wcat_t + (size_t)D_DIM * D_DIM, D_DIM, D_DIM);
  cast_transpose<<<tgrid, blk, 0, stream>>>(Wv, Wcat_t + (size_t)2 * D_DIM * D_DIM, D_DIM, D_DIM);
  cast_transpose<<<tgrid, blk, 0, stream>>>(Wo, Wo_t, D_DIM, D_DIM);

  // indexer path (fp32, K-split x4 into partials in scores scratch, reduce)
  idx_proj<<<dim3(6, T_DIM / 64, 4), blk, 0, stream>>>(x, Wq_idx, Wk_idx, Ww_idx, parts);
  idx_reduce<<<dim3(IDXP_STRIDE / 1024), blk, 0, stream>>>(parts, qi, ki, wI);
  idx_scores_rt<<<dim3(T_DIM / 64, T_DIM / 64), blk, 0, stream>>>(qi, ki, wI, scores);
  select_mask<<<dim3(T_DIM), blk, 0, stream>>>(scores, maskbits);

  // fused qkv projection: [2048][6144] = x_bf @ Wcat_t^T (8-phase 256^2 GEMM)
  gemm256_bt<<<dim3(3 * D_DIM / 256, T_DIM / 256), dim3(512), 0, stream>>>(
      x_bf, Wcat_t, qkv_bf, T_DIM, 3 * D_DIM, D_DIM);

  // v^T from strided v view (cols 4096..6143 of qkv) ; vt overwrites Wq_t
  transpose_bf<<<dim3(D_DIM / 64, T_DIM / 64), blk, 0, stream>>>(
      qkv_bf + 2 * D_DIM, vt_bf, 3 * D_DIM);

  // flash masked attention (q = qkv cols 0..2047, k = cols 2048..4095)
  flash_attn<<<dim3(T_DIM / 128, H_N), blk, 0, stream>>>(
      qkv_bf, qkv_bf + D_DIM, vt_bf, maskbits, attn_bf, 3 * D_DIM);

  // output projection -> f32
  gemm_bt<0><<<dim3(D_DIM / 128, T_DIM / 128), blk, 0, stream>>>(
      attn_bf, Wo_t, out, T_DIM, D_DIM, D_DIM);
}

// Round 7
// 485.328 us; speedup vs baseline: 1.2798x; 1.0178x over previous
//
#include <hip/hip_runtime.h>
#include <cstdint>
#include <cstddef>

#define T_DIM 2048
#define D_DIM 2048
#define HI_N 4
#define DI_N 64
#define H_N 16
#define DH_N 128
#define TOPK_N 512
#define NEG_F (-1e9f)
#define FA_NEG (-1e30f)

typedef __attribute__((ext_vector_type(8))) short short8;
typedef __attribute__((ext_vector_type(4))) float f32x4;
typedef unsigned short ushort_t;

__device__ __forceinline__ unsigned short f2bf(float f) {
  unsigned u = __float_as_uint(f);
  u += 0x7FFFu + ((u >> 16) & 1u);   // RNE
  return (unsigned short)(u >> 16);
}
__device__ __forceinline__ float bf2f(unsigned short b) {
  return __uint_as_float((unsigned)b << 16);
}

#define GLDS(g, l) __builtin_amdgcn_global_load_lds( \
    (const __attribute__((address_space(1))) unsigned int*)(g), \
    (__attribute__((address_space(3))) unsigned int*)(l), 16, 0, 0)

// Partial clone layout (floats): qi [2048][256] at 0, ki [2048][64] at 524288,
// wI [2048][4] at 655360; clone stride 663552 floats (2.654 MB).
#define IDXP_QI_F   524288
#define IDXP_KI_F   131072
#define IDXP_WI_F   8192
#define IDXP_STRIDE (IDXP_QI_F + IDXP_KI_F + IDXP_WI_F)   // 663552

// ---------------------------------------------------------------------------
// Fused indexer projections, K-split x4 (fp32). Grid (6, 32, 4): z = K chunk
// [z*512, z*512+512). 768 blocks -> 3 blocks/CU: latency hiding via TLP.
// ---------------------------------------------------------------------------
__global__ __launch_bounds__(256) void idx_proj(const float* __restrict__ x,
                                                const float* __restrict__ Wq_idx,
                                                const float* __restrict__ Wk_idx,
                                                const float* __restrict__ Ww_idx,
                                                float* __restrict__ parts) {
  __shared__ float As[2][16][64];
  __shared__ float Bs[2][16][64];
  const int bm = blockIdx.y << 6;
  const int bn_id = blockIdx.x;
  const int kbeg = blockIdx.z << 9;          // 0,512,1024,1536
  const int kend = kbeg + 512;
  float* part = parts + (size_t)blockIdx.z * IDXP_STRIDE;
  const float* B; float* C; int ldB, cb, ncols;
  if (bn_id < 4)       { B = Wq_idx; C = part;             ldB = 256; cb = bn_id << 6; ncols = 64; }
  else if (bn_id == 4) { B = Wk_idx; C = part + IDXP_QI_F; ldB = 64;  cb = 0;          ncols = 64; }
  else                 { B = Ww_idx; C = part + IDXP_QI_F + IDXP_KI_F; ldB = 4; cb = 0; ncols = 4; }
  const int tid = threadIdx.x;
  const int tx = tid & 15, ty = tid >> 4;
  const int am = tid >> 2;          // 0..63
  const int ak = (tid & 3) << 2;    // 0,4,8,12
  float acc[4][4] = {};

  // prologue: load + stage k0=kbeg into buf 0
  float4 a4 = *(const float4*)&x[(size_t)(bm + am) * 2048 + kbeg + ak];
  float4 b4 = make_float4(0, 0, 0, 0);
  if ((tx << 2) < ncols) b4 = *(const float4*)&B[(size_t)(kbeg + ty) * ldB + cb + (tx << 2)];
  As[0][ak + 0][am] = a4.x; As[0][ak + 1][am] = a4.y;
  As[0][ak + 2][am] = a4.z; As[0][ak + 3][am] = a4.w;
  *(float4*)&Bs[0][ty][tx << 2] = b4;

  int p = 0;
  for (int k0 = kbeg; k0 < kend; k0 += 16) {
    __syncthreads();  // buf p writes visible
    const bool more = (k0 + 16) < kend;
    if (more) {
      a4 = *(const float4*)&x[(size_t)(bm + am) * 2048 + k0 + 16 + ak];
      if ((tx << 2) < ncols)
        b4 = *(const float4*)&B[(size_t)(k0 + 16 + ty) * ldB + cb + (tx << 2)];
    }
#pragma unroll
    for (int kk = 0; kk < 16; ++kk) {
      float4 av4 = *(const float4*)&As[p][kk][ty << 2];
      float4 bv4 = *(const float4*)&Bs[p][kk][tx << 2];
      float av[4] = {av4.x, av4.y, av4.z, av4.w};
      float bv[4] = {bv4.x, bv4.y, bv4.z, bv4.w};
#pragma unroll
      for (int i = 0; i < 4; ++i)
#pragma unroll
        for (int j = 0; j < 4; ++j) acc[i][j] += av[i] * bv[j];
    }
    if (more) {
      As[1 - p][ak + 0][am] = a4.x; As[1 - p][ak + 1][am] = a4.y;
      As[1 - p][ak + 2][am] = a4.z; As[1 - p][ak + 3][am] = a4.w;
      *(float4*)&Bs[1 - p][ty][tx << 2] = b4;
    }
    p ^= 1;
  }
#pragma unroll
  for (int i = 0; i < 4; ++i) {
    int m = bm + (ty << 2) + i;
    int n0 = tx << 2;
    if (n0 + 3 < ncols) {
      *(float4*)&C[(size_t)m * ldB + cb + n0] =
          make_float4(acc[i][0], acc[i][1], acc[i][2], acc[i][3]);
    } else {
#pragma unroll
      for (int j = 0; j < 4; ++j)
        if (n0 + j < ncols) C[(size_t)m * ldB + cb + n0 + j] = acc[i][j];
    }
  }
}

// Reduce 4 partial clones: dst = ((p0+p1)+p2)+p3, elementwise (float4).
__global__ __launch_bounds__(256) void idx_reduce(const float* __restrict__ parts,
                                                  float* __restrict__ qi,
                                                  float* __restrict__ ki,
                                                  float* __restrict__ wI) {
  const size_t f = ((size_t)blockIdx.x * 256 + threadIdx.x) * 4;
  float4 r0 = *(const float4*)(parts + f);
  float4 r1 = *(const float4*)(parts + (size_t)IDXP_STRIDE + f);
  float4 r2 = *(const float4*)(parts + (size_t)2 * IDXP_STRIDE + f);
  float4 r3 = *(const float4*)(parts + (size_t)3 * IDXP_STRIDE + f);
  float4 r;
  r.x = ((r0.x + r1.x) + r2.x) + r3.x;
  r.y = ((r0.y + r1.y) + r2.y) + r3.y;
  r.z = ((r0.z + r1.z) + r2.z) + r3.z;
  r.w = ((r0.w + r1.w) + r2.w) + r3.w;
  float* dst;
  if (f < IDXP_QI_F)                     dst = qi + f;
  else if (f < IDXP_QI_F + IDXP_KI_F)    dst = ki + (f - IDXP_QI_F);
  else                                   dst = wI + (f - IDXP_QI_F - IDXP_KI_F);
  *(float4*)dst = r;
}

// ---------------------------------------------------------------------------
// casts / transposes
// ---------------------------------------------------------------------------
__global__ __launch_bounds__(256) void cast_bf16(const float* __restrict__ in,
                                                 ushort_t* __restrict__ out) {
  int i = (blockIdx.x * 256 + threadIdx.x) * 4;
  float4 f = *(const float4*)(in + i);
  ushort4 o;
  o.x = f2bf(f.x); o.y = f2bf(f.y); o.z = f2bf(f.z); o.w = f2bf(f.w);
  *(ushort4*)(out + i) = o;
}

// in[R][C] f32 -> out[C][R] bf16
__global__ __launch_bounds__(256) void cast_transpose(const float* __restrict__ in,
                                                      ushort_t* __restrict__ out,
                                                      int R, int C) {
  __shared__ float tile[32][33];
  const int bx = blockIdx.x * 32;
  const int by = blockIdx.y * 32;
  const int tx = threadIdx.x & 31, ty = threadIdx.x >> 5;
#pragma unroll
  for (int i = 0; i < 32; i += 8)
    tile[ty + i][tx] = in[(size_t)(by + ty + i) * C + bx + tx];
  __syncthreads();
#pragma unroll
  for (int i = 0; i < 32; i += 8)
    out[(size_t)(bx + ty + i) * R + by + tx] = f2bf(tile[tx][ty + i]);
}

// bf16 [T][ldin] -> [C][T] (transpose 64x64 tiles), ldin-strided input
__global__ __launch_bounds__(256) void transpose_bf(const ushort_t* __restrict__ in,
                                                    ushort_t* __restrict__ out,
                                                    int ldin) {
  __shared__ ushort_t tile[64][68];
  const int bx = blockIdx.x * 64;  // col base (input)
  const int by = blockIdx.y * 64;  // row base (input)
  const int tid = threadIdx.x;
#pragma unroll
  for (int p = 0; p < 4; ++p) {
    int r = p * 16 + (tid >> 4), c0 = (tid & 15) * 4;
    *(ushort4*)&tile[r][c0] = *(const ushort4*)(in + (size_t)(by + r) * ldin + bx + c0);
  }
  __syncthreads();
#pragma unroll
  for (int p = 0; p < 4; ++p) {
    int r = p * 16 + (tid >> 4), c0 = (tid & 15) * 4;
    ushort4 o;
    o.x = tile[c0 + 0][r]; o.y = tile[c0 + 1][r];
    o.z = tile[c0 + 2][r]; o.w = tile[c0 + 3][r];
    *(ushort4*)(out + (size_t)(bx + r) * T_DIM + by + c0) = o;
  }
}

// ---------------------------------------------------------------------------
// bf16 MFMA GEMM: C[M,N] = A[M,K] @ Bt[N,K]^T (m97 128^2 structure; used for Wo)
// ---------------------------------------------------------------------------
template <int OUT_BF16>
__global__ __launch_bounds__(256) void gemm_bt(const ushort_t* __restrict__ A,
                                               const ushort_t* __restrict__ Bt,
                                               void* __restrict__ C,
                                               int M, int N, int K) {
  __shared__ __attribute__((aligned(16))) ushort_t As[128 * 64];
  __shared__ __attribute__((aligned(16))) ushort_t Bs[128 * 64];
  const int bm = blockIdx.y << 7;
  const int bn = blockIdx.x << 7;
  const int tid = threadIdx.x;
  const int lane = tid & 63;
  const int wv = tid >> 6;
  const int wm = (wv >> 1) << 6;
  const int wn = (wv & 1) << 6;

  f32x4 acc[4][4] = {};

  const int sr = tid >> 3;
  const int sc = (tid & 7) << 3;
  const ushort_t* ga = A + (size_t)(bm + sr) * K + sc;
  const ushort_t* gb = Bt + (size_t)(bn + sr) * K + sc;
  const size_t rstep = (size_t)32 * K;

  for (int k0 = 0; k0 < K; k0 += 64) {
#pragma unroll
    for (int i = 0; i < 4; ++i) {
      GLDS(ga + i * rstep + k0, As + i * 2048 + tid * 8);
      GLDS(gb + i * rstep + k0, Bs + i * 2048 + tid * 8);
    }
    __syncthreads();
#pragma unroll
    for (int ks = 0; ks < 2; ++ks) {
      short8 af[4], bfr[4];
      const int kk = (ks << 5) + ((lane >> 4) << 3);
#pragma unroll
      for (int i = 0; i < 4; ++i) {
        af[i]  = *(const short8*)(As + (wm + (i << 4) + (lane & 15)) * 64 + kk);
        bfr[i] = *(const short8*)(Bs + (wn + (i << 4) + (lane & 15)) * 64 + kk);
      }
#pragma unroll
      for (int i = 0; i < 4; ++i)
#pragma unroll
        for (int j = 0; j < 4; ++j)
          acc[i][j] = __builtin_amdgcn_mfma_f32_16x16x32_bf16(af[i], bfr[j], acc[i][j], 0, 0, 0);
    }
    __syncthreads();
  }

  const int lrow = (lane >> 4) << 2;
  const int lcol = lane & 15;
#pragma unroll
  for (int i = 0; i < 4; ++i) {
    const int row = bm + wm + (i << 4) + lrow;
#pragma unroll
    for (int j = 0; j < 4; ++j) {
      const int col = bn + wn + (j << 4) + lcol;
#pragma unroll
      for (int r = 0; r < 4; ++r) {
        if (OUT_BF16)
          ((ushort_t*)C)[(size_t)(row + r) * N + col] = f2bf(acc[i][j][r]);
        else
          ((float*)C)[(size_t)(row + r) * N + col] = acc[i][j][r];
      }
    }
  }
}

// ---------------------------------------------------------------------------
// 256x256-tile 8-phase bf16 GEMM (T2+T3+T4+T5), C bf16 = A[M,K] @ Bt[N,K]^T.
// ---------------------------------------------------------------------------
__global__ __launch_bounds__(512, 2) void gemm256_bt(const ushort_t* __restrict__ A,
                                                     const ushort_t* __restrict__ Bt,
                                                     ushort_t* __restrict__ C,
                                                     int M, int N, int K) {
  __shared__ __attribute__((aligned(16))) ushort_t Ab[2][256 * 64];
  __shared__ __attribute__((aligned(16))) ushort_t Bb[2][256 * 64];
  const int bm = blockIdx.y << 8;
  const int bn = blockIdx.x << 8;
  const int tid = threadIdx.x;
  const int lane = tid & 63;
  const int wid = tid >> 6;
  const int wr = wid >> 2;          // 0..1  (M half)
  const int wc = wid & 3;           // 0..3  (N quarter)
  const int l15 = lane & 15, l4 = lane >> 4;
  const int srow = tid >> 3;        // 0..63
  const int schunk = tid & 7;
  const int swc = (schunk ^ (srow & 7)) << 3;   // pre-swizzled source col
  const int NT = K >> 6;

  f32x4 acc[8][4] = {};

#define STAGE_A(b, h, kt) { \
    const ushort_t* g_ = A + (size_t)(bm + (h) * 64 + srow) * K + (kt) * 64 + swc; \
    GLDS(g_, Ab[b] + ((h) * 64 + srow) * 64 + (schunk << 3)); \
    GLDS(g_ + (size_t)128 * K, Ab[b] + (128 + (h) * 64 + srow) * 64 + (schunk << 3)); }

#define STAGE_B(b, h, kt) { \
    const int br_ = ((srow >= 32) ? 64 : 0) + (h) * 32 + (srow & 31); \
    const ushort_t* g_ = Bt + (size_t)(bn + br_) * K + (kt) * 64 + swc; \
    GLDS(g_, Bb[b] + br_ * 64 + (schunk << 3)); \
    GLDS(g_ + (size_t)128 * K, Bb[b] + (128 + br_) * 64 + (schunk << 3)); }

#define VMW(n) asm volatile("s_waitcnt vmcnt(" #n ")" ::: "memory")

#define PHASE(b, qm, qn, STG, WT) { \
    short8 paf[4][2], pbf[2][2]; \
    _Pragma("unroll") for (int m_ = 0; m_ < 4; ++m_) { \
      const int Ra_ = wr * 128 + (qm) * 64 + m_ * 16 + l15; \
      _Pragma("unroll") for (int ks_ = 0; ks_ < 2; ++ks_) \
        paf[m_][ks_] = *(const short8*)(Ab[b] + Ra_ * 64 + ((((ks_ << 2) + l4) ^ (Ra_ & 7)) << 3)); } \
    _Pragma("unroll") for (int n_ = 0; n_ < 2; ++n_) { \
      const int Rb_ = wc * 64 + (qn) * 32 + n_ * 16 + l15; \
      _Pragma("unroll") for (int ks_ = 0; ks_ < 2; ++ks_) \
        pbf[n_][ks_] = *(const short8*)(Bb[b] + Rb_ * 64 + ((((ks_ << 2) + l4) ^ (Rb_ & 7)) << 3)); } \
    STG; \
    WT; \
    asm volatile("" ::: "memory"); \
    __builtin_amdgcn_s_barrier(); \
    asm volatile("s_waitcnt lgkmcnt(0)" ::: "memory"); \
    __builtin_amdgcn_sched_barrier(0); \
    __builtin_amdgcn_s_setprio(1); \
    _Pragma("unroll") for (int m_ = 0; m_ < 4; ++m_) \
      _Pragma("unroll") for (int n_ = 0; n_ < 2; ++n_) \
        _Pragma("unroll") for (int ks_ = 0; ks_ < 2; ++ks_) \
          acc[(qm) * 4 + m_][(qn) * 2 + n_] = __builtin_amdgcn_mfma_f32_16x16x32_bf16( \
              paf[m_][ks_], pbf[n_][ks_], acc[(qm) * 4 + m_][(qn) * 2 + n_], 0, 0, 0); \
    __builtin_amdgcn_s_setprio(0); \
    asm volatile("" ::: "memory"); \
    __builtin_amdgcn_s_barrier(); \
    asm volatile("" ::: "memory"); }

  // prologue = virtual P3..P8: tile0 all 4 halves -> b0; tile1 ev halves -> b1
  STAGE_A(0, 0, 0); STAGE_B(0, 0, 0); STAGE_A(0, 1, 0); STAGE_B(0, 1, 0);
  STAGE_A(1, 0, 1); STAGE_B(1, 0, 1);
  VMW(8);                      // confirms b0 A-ev, B-ev
  asm volatile("" ::: "memory");
  __builtin_amdgcn_s_barrier();
  asm volatile("" ::: "memory");

  for (int j = 0; j < NT / 2 - 1; ++j) {
    const int t = j * 2;
    PHASE(0, 0, 0, STAGE_A(1, 1, t + 1), VMW(6));   // confirms thru b0 B-od
    PHASE(0, 0, 1, STAGE_B(1, 1, t + 1), );
    PHASE(0, 1, 0, STAGE_A(0, 0, t + 2), );
    PHASE(0, 1, 1, STAGE_B(0, 0, t + 2), VMW(8));   // confirms thru b1 ev
    PHASE(1, 0, 0, STAGE_A(0, 1, t + 2), VMW(6));   // confirms thru b1 B-od
    PHASE(1, 0, 1, STAGE_B(0, 1, t + 2), );
    PHASE(1, 1, 0, STAGE_A(1, 0, t + 3), );
    PHASE(1, 1, 1, STAGE_B(1, 0, t + 3), VMW(8));   // confirms thru b0 ev
  }
  // tail: tiles NT-2 (b0, fully staged), NT-1 (b1: ev staged, od staged here)
  PHASE(0, 0, 0, STAGE_A(1, 1, NT - 1), VMW(6));
  PHASE(0, 0, 1, STAGE_B(1, 1, NT - 1), );
  PHASE(0, 1, 0, , );
  PHASE(0, 1, 1, , VMW(4));    // confirms b1 ev
  PHASE(1, 0, 0, , VMW(0));    // confirms b1 od
  PHASE(1, 0, 1, , );
  PHASE(1, 1, 0, , );
  PHASE(1, 1, 1, , );

#undef STAGE_A
#undef STAGE_B
#undef VMW
#undef PHASE

  // epilogue
#pragma unroll
  for (int i = 0; i < 8; ++i) {
    const int row = bm + wr * 128 + i * 16 + l4 * 4;
#pragma unroll
    for (int j2 = 0; j2 < 4; ++j2) {
      const int col = bn + wc * 64 + j2 * 16 + l15;
#pragma unroll
      for (int r = 0; r < 4; ++r)
        C[(size_t)(row + r) * N + col] = f2bf(acc[i][j2][r]);
    }
  }
}

// ---------------------------------------------------------------------------
// Lightning indexer scores, register-tiled 64x64 fp32
// ---------------------------------------------------------------------------
__global__ __launch_bounds__(256) void idx_scores_rt(const float* __restrict__ qi,
                                                     const float* __restrict__ ki,
                                                     const float* __restrict__ w,
                                                     float* __restrict__ out) {
  const int t0 = blockIdx.y << 6, s0 = blockIdx.x << 6;
  const int tid = threadIdx.x;
  const int tx = tid & 15, ty = tid >> 4;
  if (s0 > t0 + 63) {  // fully above diagonal: NEG fill (ws is poisoned!)
    const float4 nf = make_float4(NEG_F, NEG_F, NEG_F, NEG_F);
#pragma unroll
    for (int i = 0; i < 4; ++i) {
      int m = t0 + (ty << 2) + i;
      *(float4*)&out[(size_t)m * T_DIM + s0 + (tx << 2)] = nf;
    }
    return;
  }
  __shared__ float As[16][64];   // [kk][t]
  __shared__ float Bs[16][64];   // [kk][s]
  __shared__ float wsh[64][4];
  if (tid < 64) *(float4*)wsh[tid] = *(const float4*)&w[(size_t)(t0 + tid) * 4];
  const int am = tid >> 2;          // 0..63
  const int ak = (tid & 3) << 2;    // 0,4,8,12
  float oacc[4][4] = {};
#pragma unroll
  for (int h = 0; h < HI_N; ++h) {
    float dacc[4][4] = {};
    for (int k0 = 0; k0 < DI_N; k0 += 16) {
      float4 qa = *(const float4*)&qi[(size_t)(t0 + am) * 256 + h * DI_N + k0 + ak];
      float4 kb = *(const float4*)&ki[(size_t)(s0 + am) * DI_N + k0 + ak];
      __syncthreads();
      As[ak + 0][am] = qa.x; As[ak + 1][am] = qa.y;
      As[ak + 2][am] = qa.z; As[ak + 3][am] = qa.w;
      Bs[ak + 0][am] = kb.x; Bs[ak + 1][am] = kb.y;
      Bs[ak + 2][am] = kb.z; Bs[ak + 3][am] = kb.w;
      __syncthreads();
#pragma unroll
      for (int kk = 0; kk < 16; ++kk) {
        float4 a4 = *(const float4*)&As[kk][ty << 2];
        float4 b4 = *(const float4*)&Bs[kk][tx << 2];
        float av[4] = {a4.x, a4.y, a4.z, a4.w};
        float bv[4] = {b4.x, b4.y, b4.z, b4.w};
#pragma unroll
        for (int i = 0; i < 4; ++i)
#pragma unroll
          for (int j = 0; j < 4; ++j) dacc[i][j] += av[i] * bv[j];
      }
    }
#pragma unroll
    for (int i = 0; i < 4; ++i) {
      float wh = wsh[(ty << 2) + i][h];
#pragma unroll
      for (int j = 0; j < 4; ++j) oacc[i][j] += fmaxf(dacc[i][j], 0.f) * wh;
    }
  }
#pragma unroll
  for (int i = 0; i < 4; ++i) {
    int m = t0 + (ty << 2) + i;
    int n0 = s0 + (tx << 2);
    float4 r;
    r.x = (n0 + 0 > m) ? NEG_F : oacc[i][0];
    r.y = (n0 + 1 > m) ? NEG_F : oacc[i][1];
    r.z = (n0 + 2 > m) ? NEG_F : oacc[i][2];
    r.w = (n0 + 3 > m) ? NEG_F : oacc[i][3];
    *(float4*)&out[(size_t)m * T_DIM + n0] = r;
  }
}

// ---------------------------------------------------------------------------
// Per-row top-512 -> bitmask. Radix-histogram select, jax tie semantics.
// ---------------------------------------------------------------------------
__global__ __launch_bounds__(256) void select_mask(const float* __restrict__ scores,
                                                   unsigned long long* __restrict__ maskbits) {
  const int t = blockIdx.x, tid = threadIdx.x;
  __shared__ unsigned int hist[256];
  __shared__ unsigned int s_prefix, s_krem;
  __shared__ unsigned char bytes[256];
  unsigned int uv[8];
  const float* row = scores + (size_t)t * T_DIM;
  {
    float4 f0 = *(const float4*)(row + tid * 8);
    float4 f1 = *(const float4*)(row + tid * 8 + 4);
    float fv[8] = {f0.x, f0.y, f0.z, f0.w, f1.x, f1.y, f1.z, f1.w};
#pragma unroll
    for (int j = 0; j < 8; ++j) {
      unsigned u = __float_as_uint(fv[j]);
      uv[j] = (u & 0x80000000u) ? ~u : (u | 0x80000000u);
    }
  }
  if (tid == 0) { s_prefix = 0u; s_krem = TOPK_N; }
  for (int p = 0; p < 4; ++p) {
    const int sh = 24 - 8 * p;
    hist[tid] = 0;
    __syncthreads();
    const unsigned pm = p ? (0xFFFFFFFFu << (32 - 8 * p)) : 0u;
    const unsigned prefix = s_prefix;
#pragma unroll
    for (int j = 0; j < 8; ++j)
      if ((uv[j] & pm) == prefix) atomicAdd(&hist[(uv[j] >> sh) & 255], 1u);
    __syncthreads();
    if (tid == 0) {
      unsigned krem = s_krem, cum = 0;
      int b = 255;
      for (;; --b) { cum += hist[b]; if (cum >= krem) break; }
      s_prefix = prefix | ((unsigned)b << sh);
      s_krem = krem - (cum - hist[b]);
    }
    __syncthreads();
  }
  const unsigned V = s_prefix;
  const int kr = (int)s_krem;
  int eqc = 0;
#pragma unroll
  for (int j = 0; j < 8; ++j) eqc += (uv[j] == V);
  __syncthreads();
  hist[tid] = (unsigned)eqc;
  __syncthreads();
  for (int off = 1; off < 256; off <<= 1) {
    int v = (int)hist[tid];
    if (tid >= off) v += (int)hist[tid - off];
    __syncthreads();
    hist[tid] = (unsigned)v;
    __syncthreads();
  }
  int run = (int)hist[tid] - eqc;
  unsigned char byte = 0;
#pragma unroll
  for (int j = 0; j < 8; ++j) {
    bool eq = (uv[j] == V);
    bool take = (uv[j] > V) || (eq && run < kr);
    run += eq;
    byte |= (unsigned char)(take ? (1u << j) : 0u);
  }
  bytes[tid] = byte;
  __syncthreads();
  if (tid < 32) {
    unsigned long long wqw = 0;
#pragma unroll
    for (int b = 0; b < 8; ++b)
      wqw |= (unsigned long long)bytes[tid * 8 + b] << (8 * b);
    maskbits[(size_t)t * 32 + tid] = wqw;
  }
}

// ---------------------------------------------------------------------------
// Flash masked attention (bf16 MFMA), SWAPPED-operand QK^T. 8 waves (512 thr):
// wave w owns q rows [w*16, +16) -> 2 waves/SIMD (latency overlap). Per-lane
// math (s-chunking, reduce order, shfl partners) identical to the 4-wave
// version -> bitwise-same output.
// ---------------------------------------------------------------------------
__global__ __launch_bounds__(512, 2) void flash_attn(
    const ushort_t* __restrict__ q, const ushort_t* __restrict__ k,
    const ushort_t* __restrict__ vt, const unsigned long long* __restrict__ maskbits,
    ushort_t* __restrict__ attn, int ldqk) {
  __shared__ __attribute__((aligned(16))) ushort_t Ks[2][128 * 128];
  __shared__ __attribute__((aligned(16))) ushort_t Vts[128 * 128];
  __shared__ __attribute__((aligned(16))) ushort_t Ps[128 * 136];

  const int tt = blockIdx.x;
  const int h  = blockIdx.y;
  const int t0 = tt << 7;
  const int tid = threadIdx.x;
  const int lane = tid & 63;
  const int wv = tid >> 6;              // wave id 0..7; owns q rows [wv*16, +16)
  const int l15 = lane & 15, l4 = lane >> 4;
  const int e3 = l15 & 7;                                  // read-side swizzle
  const int scol = (((tid & 15) ^ ((tid >> 4) & 7)) << 3); // staging source col

  // ---- stage Q (inverse-swizzled source) into Ks[0], read q fragments ----
  {
    const ushort_t* gq = q + (size_t)(t0 + (tid >> 4)) * ldqk + h * DH_N + scol;
#pragma unroll
    for (int p = 0; p < 4; ++p)
      GLDS(gq + (size_t)p * 32 * ldqk, Ks[0] + p * 4096 + tid * 8);
  }
  asm volatile("s_waitcnt vmcnt(0)" ::: "memory");
  __builtin_amdgcn_s_barrier();
  asm volatile("" ::: "memory");
  short8 qfrag[4];   // [ks]: Q row wv*16 + l15
#pragma unroll
  for (int ks = 0; ks < 4; ++ks)
    qfrag[ks] = *(const short8*)(Ks[0] + (wv * 16 + l15) * 128 +
                                 ((((ks << 2) + l4) ^ e3) << 3));
  asm volatile("s_waitcnt lgkmcnt(0)" ::: "memory");
  __builtin_amdgcn_s_barrier();
  asm volatile("" ::: "memory");

  f32x4 acc[8] = {};                 // O^T: [d-tile], q col = l15 (wave's 16)
  float m_reg = -INFINITY;
  float l_reg = 0.f;
  const int nst = (tt < 4) ? 4 : (tt + 1);
  const float rsc = 0.08838834764831845f;  // 1/sqrt(128)

  // issue K(0) into Ks[0] (overwrites Q staging; qfrag already in registers)
  {
    const ushort_t* gk = k + (size_t)(tid >> 4) * ldqk + h * DH_N + scol;
#pragma unroll
    for (int p = 0; p < 4; ++p)
      GLDS(gk + (size_t)p * 32 * ldqk, Ks[0] + p * 4096 + tid * 8);
  }

  for (int st = 0; st < nst; ++st) {
    const int s0 = st << 7;
    const bool pf = (st + 1) < nst;

    // [A] all waves done with PV of st-1 -> Vts free for overwrite
    asm volatile("" ::: "memory");
    __builtin_amdgcn_s_barrier();
    asm volatile("" ::: "memory");

    // [B] mask words (2/lane): q row = wv*16 + l15
    unsigned long long mw[2];
    {
      const int wbase = s0 >> 6;
#pragma unroll
      for (int wd = 0; wd < 2; ++wd)
        mw[wd] = maskbits[(size_t)(t0 + wv * 16 + l15) * 32 + wbase + wd];
    }
    // [C] V(st) -> Vts (4 loads); consumed in PV (latency hidden)
    {
      const ushort_t* gv = vt + (size_t)(h * DH_N + (tid >> 4)) * T_DIM + s0 + scol;
#pragma unroll
      for (int p = 0; p < 4; ++p)
        GLDS(gv + (size_t)p * 32 * T_DIM, Vts + p * 4096 + tid * 8);
    }
    asm volatile("" ::: "memory");  // order: V strictly before K-prefetch
    // [D] K(st+1) prefetch into other buffer (4 loads)
    if (pf) {
      const ushort_t* gk = k + (size_t)(s0 + 128 + (tid >> 4)) * ldqk + h * DH_N + scol;
      ushort_t* dst = Ks[(st + 1) & 1];
#pragma unroll
      for (int p = 0; p < 4; ++p)
        GLDS(gk + (size_t)p * 32 * ldqk, dst + p * 4096 + tid * 8);
    }
    // [E] drain K(st) only: 2(mask)+4(V)+4(K+1) newer ops stay in flight
    if (pf) asm volatile("s_waitcnt vmcnt(10)" ::: "memory");
    else    asm volatile("s_waitcnt vmcnt(6)" ::: "memory");
    __builtin_amdgcn_s_barrier();   // [F] K(st) visible to all waves
    asm volatile("" ::: "memory");

    // ---- QK^T (swapped): sacc[i] rows = s, col = q (l15) ----
    const ushort_t* Kb = Ks[st & 1];
    f32x4 sacc[8] = {};
    __builtin_amdgcn_s_setprio(1);
#pragma unroll
    for (int ks = 0; ks < 4; ++ks) {
      const int co = ((((ks << 2) + l4) ^ e3) << 3);
      short8 af[8];
#pragma unroll
      for (int i = 0; i < 8; ++i)
        af[i] = *(const short8*)(Kb + (i * 16 + l15) * 128 + co);
#pragma unroll
      for (int i = 0; i < 8; ++i)
        sacc[i] = __builtin_amdgcn_mfma_f32_16x16x32_bf16(af[i], qfrag[ks], sacc[i], 0, 0, 0);
    }
    __builtin_amdgcn_s_setprio(0);

    // ---- mask + scale: s = i*16 + l4*4 + r ----
#pragma unroll
    for (int i = 0; i < 8; ++i)
#pragma unroll
      for (int r = 0; r < 4; ++r) {
        bool sel = (mw[i >> 2] >> ((i & 3) * 16 + l4 * 4 + r)) & 1;
        sacc[i][r] = sel ? sacc[i][r] * rsc : FA_NEG;
      }

    // ---- in-register online softmax (single q column = l15) ----
    float alpha;
    {
      float pm = sacc[0][0];
#pragma unroll
      for (int i = 0; i < 8; ++i)
#pragma unroll
        for (int r = 0; r < 4; ++r) pm = fmaxf(pm, sacc[i][r]);
      pm = fmaxf(pm, __shfl_xor(pm, 16));
      pm = fmaxf(pm, __shfl_xor(pm, 32));
      const float mn = fmaxf(m_reg, pm);
      alpha = __expf(m_reg - mn);
      float ps = 0.f;
#pragma unroll
      for (int i = 0; i < 8; ++i)
#pragma unroll
        for (int r = 0; r < 4; ++r) {
          float s = sacc[i][r];
          float pv = (s <= -1e29f) ? 0.f : __expf(s - mn);
          sacc[i][r] = pv;
          ps += pv;
        }
      ps += __shfl_xor(ps, 16);
      ps += __shfl_xor(ps, 32);
      l_reg = alpha * l_reg + ps;
      m_reg = mn;
    }
    // rescale accumulated O^T (col = q)
#pragma unroll
    for (int i = 0; i < 8; ++i)
#pragma unroll
      for (int r = 0; r < 4; ++r) acc[i][r] *= alpha;

    // ---- P -> Ps[q][s] (per-wave-disjoint rows, b64 writes) ----
#pragma unroll
    for (int i = 0; i < 8; ++i) {
      ushort4 pk;
      pk.x = f2bf(sacc[i][0]); pk.y = f2bf(sacc[i][1]);
      pk.z = f2bf(sacc[i][2]); pk.w = f2bf(sacc[i][3]);
      *(ushort4*)&Ps[(wv * 16 + l15) * 136 + i * 16 + l4 * 4] = pk;
    }

    // [K] drain V(st), keep K(st+1) in flight
    if (pf) asm volatile("s_waitcnt vmcnt(4)" ::: "memory");
    else    asm volatile("s_waitcnt vmcnt(0)" ::: "memory");
    __builtin_amdgcn_s_barrier();   // [L] Vts visible
    asm volatile("" ::: "memory");

    // ---- PV: acc[i] += V^T[d-tile i] . P[wave's q-tile] ----
    __builtin_amdgcn_s_setprio(1);
#pragma unroll
    for (int ks = 0; ks < 4; ++ks) {
      const int co = ((((ks << 2) + l4) ^ e3) << 3);
      short8 af[8], bq;
#pragma unroll
      for (int i = 0; i < 8; ++i)
        af[i] = *(const short8*)(Vts + (i * 16 + l15) * 128 + co);
      bq = *(const short8*)(Ps + (wv * 16 + l15) * 136 + ks * 32 + l4 * 8);
#pragma unroll
      for (int i = 0; i < 8; ++i)
        acc[i] = __builtin_amdgcn_mfma_f32_16x16x32_bf16(af[i], bq, acc[i], 0, 0, 0);
    }
    __builtin_amdgcn_s_setprio(0);
  }

  // ---- epilogue: normalize, stage to Ps[q][d], coalesced store ----
  const float linv = 1.f / l_reg;
#pragma unroll
  for (int i = 0; i < 8; ++i) {
    ushort4 pk;
    pk.x = f2bf(acc[i][0] * linv);
    pk.y = f2bf(acc[i][1] * linv);
    pk.z = f2bf(acc[i][2] * linv);
    pk.w = f2bf(acc[i][3] * linv);
    *(ushort4*)&Ps[(wv * 16 + l15) * 136 + i * 16 + l4 * 4] = pk;
  }
  __syncthreads();
#pragma unroll
  for (int p = 0; p < 4; ++p) {
    int rw = p * 32 + (tid >> 4);
    int d0 = (tid & 15) * 8;
    *(ulonglong2*)(attn + (size_t)(t0 + rw) * D_DIM + h * DH_N + d0) =
        *(const ulonglong2*)(Ps + rw * 136 + d0);
  }
}

// ---------------------------------------------------------------------------
extern "C" void kernel_launch(void* const* d_in, const int* in_sizes, int n_in,
                              void* d_out, int out_size, void* d_ws, size_t ws_size,
                              hipStream_t stream) {
  (void)in_sizes; (void)n_in; (void)out_size; (void)ws_size;
  const float* x      = (const float*)d_in[0];
  const float* Wq_idx = (const float*)d_in[1];
  const float* Wk_idx = (const float*)d_in[2];
  const float* Ww_idx = (const float*)d_in[3];
  const float* Wq     = (const float*)d_in[4];
  const float* Wk     = (const float*)d_in[5];
  const float* Wv     = (const float*)d_in[6];
  const float* Wo     = (const float*)d_in[7];
  float* out = (float*)d_out;

  char* ws = (char*)d_ws;
  const size_t MB = 1ull << 20;
  // layout: [0,10.7) idx partials (transient) -> scores f32 [0,16) -> qkv_bf
  float*    parts   = (float*)(ws);
  float*    scores  = (float*)(ws);
  ushort_t* qkv_bf  = (ushort_t*)(ws);
  unsigned long long* maskbits = (unsigned long long*)(ws + 25 * MB + 512 * 1024);
  ushort_t* x_bf    = (ushort_t*)(ws + 26 * MB);
  ushort_t* Wcat_t  = (ushort_t*)(ws + 34 * MB);  // 3 x [2048][2048]
  ushort_t* vt_bf   = (ushort_t*)(ws + 34 * MB);
  ushort_t* attn_bf = (ushort_t*)(ws + 42 * MB);
  ushort_t* Wo_t    = (ushort_t*)(ws + 58 * MB);
  float*    qi      = (float*)(ws + 66 * MB);
  float*    ki      = (float*)(ws + 68 * MB);
  float*    wI      = (float*)(ws + 68 * MB + 512 * 1024);

  const dim3 blk(256);
  const dim3 tgrid(D_DIM / 32, D_DIM / 32);

  cast_bf16<<<dim3((D_DIM * T_DIM) / 1024), blk, 0, stream>>>(x, x_bf);
  cast_transpose<<<tgrid, blk, 0, stream>>>(Wq, Wcat_t, D_DIM, D_DIM);
  cast_transpose<<<tgrid, blk, 0, stream>>>(Wk, Wcat_t + (size_t)D_DIM * D_DIM, D_DIM, D_DIM);
  cast_transpose<<<tgrid, blk, 0, stream>>>(Wv, Wcat_t + (size_t)2 * D_DIM * D_DIM, D_DIM, D_DIM);
  cast_transpose<<<tgrid, blk, 0, stream>>>(Wo, Wo_t, D_DIM, D_DIM);

  // indexer path (fp32, K-split x4 into partials in scores scratch, reduce)
  idx_proj<<<dim3(6, T_DIM / 64, 4), blk, 0, stream>>>(x, Wq_idx, Wk_idx, Ww_idx, parts);
  idx_reduce<<<dim3(IDXP_STRIDE / 1024), blk, 0, stream>>>(parts, qi, ki, wI);
  idx_scores_rt<<<dim3(T_DIM / 64, T_DIM / 64), blk, 0, stream>>>(qi, ki, wI, scores);
  select_mask<<<dim3(T_DIM), blk, 0, stream>>>(scores, maskbits);

  // fused qkv projection: [2048][6144] = x_bf @ Wcat_t^T (8-phase 256^2 GEMM)
  gemm256_bt<<<dim3(3 * D_DIM / 256, T_DIM / 256), dim3(512), 0, stream>>>(
      x_bf, Wcat_t, qkv_bf, T_DIM, 3 * D_DIM, D_DIM);

  // v^T from strided v view (cols 4096..6143 of qkv) ; vt overwrites Wq_t
  transpose_bf<<<dim3(D_DIM / 64, T_DIM / 64), blk, 0, stream>>>(
      qkv_bf + 2 * D_DIM, vt_bf, 3 * D_DIM);

  // flash masked attention (q = qkv cols 0..2047, k = cols 2048..4095)
  flash_attn<<<dim3(T_DIM / 128, H_N), dim3(512), 0, stream>>>(
      qkv_bf, qkv_bf + D_DIM, vt_bf, maskbits, attn_bf, 3 * D_DIM);

  // output projection -> f32
  gemm_bt<0><<<dim3(D_DIM / 128, T_DIM / 128), blk, 0, stream>>>(
      attn_bf, Wo_t, out, T_DIM, D_DIM, D_DIM);
}